// Round 6
// baseline (1609.729 us; speedup 1.0000x reference)
//
#include <hip/hip_runtime.h>

// GAT 2-layer v5: fp16 rows + MFMA gemm + bucketed (64-node) LDS-accum agg.
// N=50000, E=800000 (+N self loops), H=4 heads, C=32, HC=128.

typedef float f32x4 __attribute__((ext_vector_type(4)));
typedef _Float16 f16x8 __attribute__((ext_vector_type(8)));
typedef _Float16 f16x2 __attribute__((ext_vector_type(2)));
typedef _Float16 halfT;

#define SCHUNK 16384
#define MAXNB 1024  // buckets of 64 nodes; supports N <= 65536

// ---------------- casts -----------------------------------------------------
__global__ __launch_bounds__(256) void cast_x_kernel(
    const float* __restrict__ in, halfT* __restrict__ outp, int total8) {
  int i = blockIdx.x * 256 + threadIdx.x;
  if (i >= total8) return;
  f32x4 a = ((const f32x4*)in)[i * 2];
  f32x4 b = ((const f32x4*)in)[i * 2 + 1];
  f16x8 o;
  o[0] = (halfT)a.x; o[1] = (halfT)a.y; o[2] = (halfT)a.z; o[3] = (halfT)a.w;
  o[4] = (halfT)b.x; o[5] = (halfT)b.y; o[6] = (halfT)b.z; o[7] = (halfT)b.w;
  ((f16x8*)outp)[i] = o;
}

// W [128][128] fp32 -> B-fragment-ordered fp16
__global__ __launch_bounds__(256) void cast_w_kernel(
    const float* __restrict__ W, halfT* __restrict__ wf) {
  int idx = blockIdx.x * 256 + threadIdx.x;  // 0..16383
  int j = idx & 7, lane = (idx >> 3) & 63, ks = (idx >> 9) & 3, nt = idx >> 11;
  int k = ks * 32 + (lane >> 4) * 8 + j;
  int n = nt * 16 + (lane & 15);
  wf[idx] = (halfT)W[k * 128 + n];
}

// ------- MFMA GEMM + scores (unchanged from v4) -----------------------------
__global__ __launch_bounds__(256) void gemm_mfma_kernel(
    const halfT* __restrict__ Xh, const halfT* __restrict__ Wf,
    const float* __restrict__ a_src, const float* __restrict__ a_dst,
    halfT* __restrict__ Hh, float* __restrict__ ssrc, float* __restrict__ sdst,
    int N) {
  __shared__ f16x8 wlds[2048];
  __shared__ float cst[4][16][134];
  int t = threadIdx.x;
  for (int i = t; i < 2048; i += 256) wlds[i] = ((const f16x8*)Wf)[i];
  __syncthreads();

  int w = t >> 6, lane = t & 63;
  int growbase = blockIdx.x * 64 + w * 16;
  const f16x8* xrow =
      (const f16x8*)(Xh + (size_t)(growbase + (lane & 15)) * 128 + (lane >> 4) * 8);

  f32x4 acc[8];
#pragma unroll
  for (int nt = 0; nt < 8; ++nt) acc[nt] = (f32x4){0.f, 0.f, 0.f, 0.f};

#pragma unroll
  for (int ks = 0; ks < 4; ++ks) {
    f16x8 af = xrow[ks * 4];
#pragma unroll
    for (int nt = 0; nt < 8; ++nt)
      acc[nt] = __builtin_amdgcn_mfma_f32_16x16x32_f16(
          af, wlds[(nt * 4 + ks) * 64 + lane], acc[nt], 0, 0, 0);
  }

#pragma unroll
  for (int nt = 0; nt < 8; ++nt)
#pragma unroll
    for (int j = 0; j < 4; ++j)
      cst[w][(lane >> 4) * 4 + j][nt * 16 + (lane & 15)] = acc[nt][j];
  __syncthreads();

  int r = lane >> 2, q = lane & 3;
  int grow = growbase + r;
  if (grow >= N) return;
  const float* cp = &cst[w][r][q * 32];
  const float* asp = a_src + q * 32;
  const float* adp = a_dst + q * 32;
  f16x8* hp = (f16x8*)(Hh + (size_t)grow * 128 + q * 32);
  float ss = 0.f, sd = 0.f;
#pragma unroll
  for (int g = 0; g < 4; ++g) {
    f16x8 hv;
#pragma unroll
    for (int jj = 0; jj < 8; ++jj) {
      float v = cp[g * 8 + jj];
      ss = fmaf(v, asp[g * 8 + jj], ss);
      sd = fmaf(v, adp[g * 8 + jj], sd);
      hv[jj] = (halfT)v;
    }
    hp[g] = hv;
  }
  ssrc[grow * 4 + q] = ss;
  sdst[grow * 4 + q] = sd;
}

// ---------------- bucket build ----------------------------------------------
__global__ __launch_bounds__(256) void hist64_kernel(
    const int* __restrict__ dst, int* __restrict__ bcnt, int Etot, int E, int NB) {
  __shared__ int h[MAXNB];
  for (int i = threadIdx.x; i < NB; i += 256) h[i] = 0;
  __syncthreads();
  for (int e = blockIdx.x * 256 + threadIdx.x; e < Etot; e += gridDim.x * 256) {
    int d = (e < E) ? dst[e] : (e - E);
    atomicAdd(&h[d >> 6], 1);
  }
  __syncthreads();
  for (int i = threadIdx.x; i < NB; i += 256)
    if (h[i]) atomicAdd(&bcnt[i], h[i]);
}

__global__ __launch_bounds__(256) void bscan_kernel(
    const int* __restrict__ bcnt, int* __restrict__ bbase,
    int* __restrict__ bcur, int NB, int Etot) {
  __shared__ int tsum[256];
  int t = threadIdx.x;
  int v[4];
  int s = 0;
#pragma unroll
  for (int j = 0; j < 4; ++j) {
    int i = t * 4 + j;
    v[j] = (i < NB) ? bcnt[i] : 0;
    s += v[j];
  }
  tsum[t] = s;
  __syncthreads();
  for (int off = 1; off < 256; off <<= 1) {
    int u = (t >= off) ? tsum[t - off] : 0;
    __syncthreads();
    tsum[t] += u;
    __syncthreads();
  }
  int run = tsum[t] - s;
#pragma unroll
  for (int j = 0; j < 4; ++j) {
    int i = t * 4 + j;
    if (i < NB) { bbase[i] = run; bcur[i] = run; }
    run += v[j];
  }
  if (t == 0) bbase[NB] = Etot;
}

// per-block runs reserved with one global atomic per (block,bucket): writes
// land in block-exclusive contiguous windows (no cross-XCD line sharing).
__global__ __launch_bounds__(256) void scatter64_kernel(
    const int* __restrict__ src, const int* __restrict__ dst,
    int* __restrict__ bcur, unsigned* __restrict__ epack,
    int Etot, int E, int NB) {
  __shared__ int h[MAXNB];
  __shared__ int cur[MAXNB];
  int t = threadIdx.x;
  int e0 = blockIdx.x * SCHUNK;
  int e1 = min(e0 + SCHUNK, Etot);
  for (int i = t; i < NB; i += 256) h[i] = 0;
  __syncthreads();
  for (int e = e0 + t; e < e1; e += 256) {
    int d = (e < E) ? dst[e] : (e - E);
    atomicAdd(&h[d >> 6], 1);
  }
  __syncthreads();
  for (int i = t; i < NB; i += 256) {
    int c = h[i];
    cur[i] = c ? atomicAdd(&bcur[i], c) : 0;
  }
  __syncthreads();
  for (int e = e0 + t; e < e1; e += 256) {
    int s = (e < E) ? src[e] : (e - E);
    int d = (e < E) ? dst[e] : (e - E);
    int b = d >> 6;
    int pos = atomicAdd(&cur[b], 1);
    epack[pos] = ((unsigned)(d & 63) << 26) | (unsigned)s;
  }
}

// ---------------- bucket aggregation: one block per 64-node bucket ----------
// LDS fp32 accumulators; per edge: one wave does exp + 256B row gather +
// 2 LDS float atomics/lane. Epilogue: normalize+bias+relu (+lin_w dot).
template <int FINAL>
__global__ __launch_bounds__(256) void bucket_agg_kernel(
    const unsigned* __restrict__ epack, const int* __restrict__ bbase,
    const float* __restrict__ ssrc, const float* __restrict__ sdst,
    const halfT* __restrict__ Hin, const float* __restrict__ bias,
    const float* __restrict__ lw, const float* __restrict__ lb,
    float* __restrict__ out, int N) {
  __shared__ float acc[64][128];
  __shared__ float zb[64][4];
  int t = threadIdx.x;
  int b = blockIdx.x;
  int nb0 = b * 64;

  for (int i = t; i < 64 * 32; i += 256) ((f32x4*)acc)[i] = (f32x4){0.f, 0.f, 0.f, 0.f};
  if (t < 64) *((f32x4*)&zb[t][0]) = (f32x4){0.f, 0.f, 0.f, 0.f};
  __syncthreads();

  int estart = bbase[b], eend = bbase[b + 1];
  int wid = t >> 6, lane = t & 63, head = lane >> 4;

  int idx = estart + wid;
  for (; idx + 4 < eend; idx += 8) {
    unsigned pk0 = epack[idx], pk1 = epack[idx + 4];
    int s0 = pk0 & 0x3FFFFFF, dl0 = pk0 >> 26;
    int s1 = pk1 & 0x3FFFFFF, dl1 = pk1 >> 26;
    float ss0 = ssrc[s0 * 4 + head], sd0 = sdst[(nb0 + dl0) * 4 + head];
    float ss1 = ssrc[s1 * 4 + head], sd1 = sdst[(nb0 + dl1) * 4 + head];
    f16x2 v0 = ((const f16x2*)(Hin + ((size_t)s0 << 7)))[lane];
    f16x2 v1 = ((const f16x2*)(Hin + ((size_t)s1 << 7)))[lane];
    float e0 = ss0 + sd0; e0 = e0 > 0.f ? e0 : 0.2f * e0;
    float e1 = ss1 + sd1; e1 = e1 > 0.f ? e1 : 0.2f * e1;
    float p0 = __expf(e0), p1 = __expf(e1);
    atomicAdd(&acc[dl0][2 * lane], p0 * (float)v0[0]);
    atomicAdd(&acc[dl0][2 * lane + 1], p0 * (float)v0[1]);
    atomicAdd(&acc[dl1][2 * lane], p1 * (float)v1[0]);
    atomicAdd(&acc[dl1][2 * lane + 1], p1 * (float)v1[1]);
    if ((lane & 15) == 0) {
      atomicAdd(&zb[dl0][head], p0);
      atomicAdd(&zb[dl1][head], p1);
    }
  }
  for (; idx < eend; idx += 4) {
    unsigned pk0 = epack[idx];
    int s0 = pk0 & 0x3FFFFFF, dl0 = pk0 >> 26;
    float ss0 = ssrc[s0 * 4 + head], sd0 = sdst[(nb0 + dl0) * 4 + head];
    f16x2 v0 = ((const f16x2*)(Hin + ((size_t)s0 << 7)))[lane];
    float e0 = ss0 + sd0; e0 = e0 > 0.f ? e0 : 0.2f * e0;
    float p0 = __expf(e0);
    atomicAdd(&acc[dl0][2 * lane], p0 * (float)v0[0]);
    atomicAdd(&acc[dl0][2 * lane + 1], p0 * (float)v0[1]);
    if ((lane & 15) == 0) atomicAdd(&zb[dl0][head], p0);
  }
  __syncthreads();

  // epilogue: iteration k -> wave `wid` handles node 4k+wid, lane = feature pair
  for (int i = t; i < 64 * 64; i += 256) {
    int node = i >> 6, l2 = i & 63, hh = l2 >> 4;
    int gn = nb0 + node;
    if (gn >= N) continue;
    float rz = 1.f / (zb[node][hh] + 1e-16f);
    float2 bb = ((const float2*)bias)[l2];
    float ox = fmaxf(fmaf(acc[node][2 * l2], rz, bb.x), 0.f);
    float oy = fmaxf(fmaf(acc[node][2 * l2 + 1], rz, bb.y), 0.f);
    if (FINAL) {
      float2 ww = ((const float2*)lw)[l2];
      float v = ox * ww.x + oy * ww.y;
#pragma unroll
      for (int off = 32; off; off >>= 1) v += __shfl_down(v, off);
      if ((l2 & 63) == 0) out[gn] = v + lb[0];
    } else {
      ((f16x2*)out)[(size_t)gn * 64 + l2] = (f16x2){(halfT)ox, (halfT)oy};
    }
  }
}

extern "C" void kernel_launch(void* const* d_in, const int* in_sizes, int n_in,
                              void* d_out, int out_size, void* d_ws, size_t ws_size,
                              hipStream_t stream) {
  const float* x   = (const float*)d_in[0];
  const int*   src = (const int*)d_in[1];
  const int*   dst = (const int*)d_in[2];
  const float* W1  = (const float*)d_in[3];
  const float* as1 = (const float*)d_in[4];
  const float* ad1 = (const float*)d_in[5];
  const float* b1  = (const float*)d_in[6];
  const float* W2  = (const float*)d_in[7];
  const float* as2 = (const float*)d_in[8];
  const float* ad2 = (const float*)d_in[9];
  const float* b2  = (const float*)d_in[10];
  const float* lw  = (const float*)d_in[11];
  const float* lb  = (const float*)d_in[12];

  int N = in_sizes[0] / 128;
  int E = in_sizes[1];
  int Etot = E + N;
  int NB = (N + 63) / 64;          // 64-node buckets
  int nb64 = (N + 63) / 64;
  int Npad = nb64 * 64;

  char* w = (char*)d_ws;
  halfT* x16  = (halfT*)w; w += (size_t)Npad * 128 * 2;
  halfT* h16  = (halfT*)w; w += (size_t)Npad * 128 * 2;
  halfT* xb16 = (halfT*)w; w += (size_t)Npad * 128 * 2;
  halfT* wf1  = (halfT*)w; w += 16384 * 2;
  halfT* wf2  = (halfT*)w; w += 16384 * 2;
  float* ssrc = (float*)w; w += (size_t)N * 4 * 4;
  float* sdst = (float*)w; w += (size_t)N * 4 * 4;
  int* bcnt   = (int*)w;   w += (MAXNB + 1) * 4;
  int* bbase  = (int*)w;   w += (MAXNB + 1) * 4;
  int* bcur   = (int*)w;   w += (MAXNB + 1) * 4;
  unsigned* epack = (unsigned*)w; w += (size_t)Etot * 4;

  int cx_grid  = (N * 128 / 8 + 255) / 256;
  int sc_grid  = (Etot + SCHUNK - 1) / SCHUNK;

  // ---- casts ----
  cast_x_kernel<<<cx_grid, 256, 0, stream>>>(x, x16, N * 128 / 8);
  cast_w_kernel<<<64, 256, 0, stream>>>(W1, wf1);
  cast_w_kernel<<<64, 256, 0, stream>>>(W2, wf2);

  // ---- bucket build (reused by both layers) ----
  hipMemsetAsync(bcnt, 0, (size_t)(MAXNB + 1) * 4, stream);
  hist64_kernel<<<512, 256, 0, stream>>>(dst, bcnt, Etot, E, NB);
  bscan_kernel<<<1, 256, 0, stream>>>(bcnt, bbase, bcur, NB, Etot);
  scatter64_kernel<<<sc_grid, 256, 0, stream>>>(src, dst, bcur, epack, Etot, E, NB);

  // ---- Layer 1 ----
  gemm_mfma_kernel<<<nb64, 256, 0, stream>>>(x16, wf1, as1, ad1, h16, ssrc, sdst, N);
  bucket_agg_kernel<0><<<NB, 256, 0, stream>>>(epack, bbase, ssrc, sdst, h16,
                                               b1, nullptr, nullptr, (float*)xb16, N);

  // ---- Layer 2 (fused final linear) ----
  gemm_mfma_kernel<<<nb64, 256, 0, stream>>>(xb16, wf2, as2, ad2, h16, ssrc, sdst, N);
  bucket_agg_kernel<1><<<NB, 256, 0, stream>>>(epack, bbase, ssrc, sdst, h16,
                                               b2, lw, lb, (float*)d_out, N);
}

// Round 8
// 205.293 us; speedup vs baseline: 7.8411x; 7.8411x over previous
//
#include <hip/hip_runtime.h>

// GAT 2-layer v7: v6 with bucket_sort race fix (cstart snapshot).
// fp16 rows + MFMA gemm + per-wave CSR gather agg; CSR via bucket-windowed
// scatter + per-bucket LDS counting sort.
// N=50000, E=800000 (+N self loops), H=4 heads, C=32, HC=128.

typedef float f32x4 __attribute__((ext_vector_type(4)));
typedef _Float16 f16x8 __attribute__((ext_vector_type(8)));
typedef _Float16 f16x2 __attribute__((ext_vector_type(2)));
typedef _Float16 halfT;

#define SCHUNK 16384
#define MAXNB 1024  // 64-node buckets; supports N <= 65536

// ---------------- casts -----------------------------------------------------
__global__ __launch_bounds__(256) void cast_x_kernel(
    const float* __restrict__ in, halfT* __restrict__ outp, int total8) {
  int i = blockIdx.x * 256 + threadIdx.x;
  if (i >= total8) return;
  f32x4 a = ((const f32x4*)in)[i * 2];
  f32x4 b = ((const f32x4*)in)[i * 2 + 1];
  f16x8 o;
  o[0] = (halfT)a.x; o[1] = (halfT)a.y; o[2] = (halfT)a.z; o[3] = (halfT)a.w;
  o[4] = (halfT)b.x; o[5] = (halfT)b.y; o[6] = (halfT)b.z; o[7] = (halfT)b.w;
  ((f16x8*)outp)[i] = o;
}

// W [128][128] fp32 -> B-fragment-ordered fp16
__global__ __launch_bounds__(256) void cast_w_kernel(
    const float* __restrict__ W, halfT* __restrict__ wf) {
  int idx = blockIdx.x * 256 + threadIdx.x;  // 0..16383
  int j = idx & 7, lane = (idx >> 3) & 63, ks = (idx >> 9) & 3, nt = idx >> 11;
  int k = ks * 32 + (lane >> 4) * 8 + j;
  int n = nt * 16 + (lane & 15);
  wf[idx] = (halfT)W[k * 128 + n];
}

// ------- MFMA GEMM + scores -------------------------------------------------
__global__ __launch_bounds__(256) void gemm_mfma_kernel(
    const halfT* __restrict__ Xh, const halfT* __restrict__ Wf,
    const float* __restrict__ a_src, const float* __restrict__ a_dst,
    halfT* __restrict__ Hh, float* __restrict__ ssrc, float* __restrict__ sdst,
    int N) {
  __shared__ f16x8 wlds[2048];
  __shared__ float cst[4][16][134];
  int t = threadIdx.x;
  for (int i = t; i < 2048; i += 256) wlds[i] = ((const f16x8*)Wf)[i];
  __syncthreads();

  int w = t >> 6, lane = t & 63;
  int growbase = blockIdx.x * 64 + w * 16;
  const f16x8* xrow =
      (const f16x8*)(Xh + (size_t)(growbase + (lane & 15)) * 128 + (lane >> 4) * 8);

  f32x4 acc[8];
#pragma unroll
  for (int nt = 0; nt < 8; ++nt) acc[nt] = (f32x4){0.f, 0.f, 0.f, 0.f};

#pragma unroll
  for (int ks = 0; ks < 4; ++ks) {
    f16x8 af = xrow[ks * 4];
#pragma unroll
    for (int nt = 0; nt < 8; ++nt)
      acc[nt] = __builtin_amdgcn_mfma_f32_16x16x32_f16(
          af, wlds[(nt * 4 + ks) * 64 + lane], acc[nt], 0, 0, 0);
  }

#pragma unroll
  for (int nt = 0; nt < 8; ++nt)
#pragma unroll
    for (int j = 0; j < 4; ++j)
      cst[w][(lane >> 4) * 4 + j][nt * 16 + (lane & 15)] = acc[nt][j];
  __syncthreads();

  int r = lane >> 2, q = lane & 3;
  int grow = growbase + r;
  if (grow >= N) return;
  const float* cp = &cst[w][r][q * 32];
  const float* asp = a_src + q * 32;
  const float* adp = a_dst + q * 32;
  f16x8* hp = (f16x8*)(Hh + (size_t)grow * 128 + q * 32);
  float ss = 0.f, sd = 0.f;
#pragma unroll
  for (int g = 0; g < 4; ++g) {
    f16x8 hv;
#pragma unroll
    for (int jj = 0; jj < 8; ++jj) {
      float v = cp[g * 8 + jj];
      ss = fmaf(v, asp[g * 8 + jj], ss);
      sd = fmaf(v, adp[g * 8 + jj], sd);
      hv[jj] = (halfT)v;
    }
    hp[g] = hv;
  }
  ssrc[grow * 4 + q] = ss;
  sdst[grow * 4 + q] = sd;
}

// ---------------- bucket build ----------------------------------------------
__global__ __launch_bounds__(256) void hist64_kernel(
    const int* __restrict__ dst, int* __restrict__ bcnt, int Etot, int E, int NB) {
  __shared__ int h[MAXNB];
  for (int i = threadIdx.x; i < NB; i += 256) h[i] = 0;
  __syncthreads();
  for (int e = blockIdx.x * 256 + threadIdx.x; e < Etot; e += gridDim.x * 256) {
    int d = (e < E) ? dst[e] : (e - E);
    atomicAdd(&h[d >> 6], 1);
  }
  __syncthreads();
  for (int i = threadIdx.x; i < NB; i += 256)
    if (h[i]) atomicAdd(&bcnt[i], h[i]);
}

__global__ __launch_bounds__(256) void bscan_kernel(
    const int* __restrict__ bcnt, int* __restrict__ bbase,
    int* __restrict__ bcur, int* __restrict__ rowptr, int NB, int Etot, int N) {
  __shared__ int tsum[256];
  int t = threadIdx.x;
  int v[4];
  int s = 0;
#pragma unroll
  for (int j = 0; j < 4; ++j) {
    int i = t * 4 + j;
    v[j] = (i < NB) ? bcnt[i] : 0;
    s += v[j];
  }
  tsum[t] = s;
  __syncthreads();
  for (int off = 1; off < 256; off <<= 1) {
    int u = (t >= off) ? tsum[t - off] : 0;
    __syncthreads();
    tsum[t] += u;
    __syncthreads();
  }
  int run = tsum[t] - s;
#pragma unroll
  for (int j = 0; j < 4; ++j) {
    int i = t * 4 + j;
    if (i < NB) { bbase[i] = run; bcur[i] = run; }
    run += v[j];
  }
  if (t == 0) { bbase[NB] = Etot; rowptr[N] = Etot; }
}

// bucket-windowed scatter: block-exclusive contiguous runs per (block,bucket)
__global__ __launch_bounds__(256) void scatter64_kernel(
    const int* __restrict__ src, const int* __restrict__ dst,
    int* __restrict__ bcur, unsigned* __restrict__ epack,
    int Etot, int E, int NB) {
  __shared__ int h[MAXNB];
  __shared__ int cur[MAXNB];
  int t = threadIdx.x;
  int e0 = blockIdx.x * SCHUNK;
  int e1 = min(e0 + SCHUNK, Etot);
  for (int i = t; i < NB; i += 256) h[i] = 0;
  __syncthreads();
  for (int e = e0 + t; e < e1; e += 256) {
    int d = (e < E) ? dst[e] : (e - E);
    atomicAdd(&h[d >> 6], 1);
  }
  __syncthreads();
  for (int i = t; i < NB; i += 256) {
    int c = h[i];
    cur[i] = c ? atomicAdd(&bcur[i], c) : 0;
  }
  __syncthreads();
  for (int e = e0 + t; e < e1; e += 256) {
    int s = (e < E) ? src[e] : (e - E);
    int d = (e < E) ? dst[e] : (e - E);
    int b = d >> 6;
    int pos = atomicAdd(&cur[b], 1);
    epack[pos] = ((unsigned)(d & 63) << 26) | (unsigned)s;
  }
}

// per-bucket counting sort: epack window -> node-grouped csr_src + rowptr.
// cstart[] snapshots the scan so rowptr publication can't race the scatter
// loop's cur[] increments (R6 bug).
__global__ __launch_bounds__(256) void bucket_sort_kernel(
    const unsigned* __restrict__ epack, const int* __restrict__ bbase,
    int* __restrict__ csr_src, int* __restrict__ rowptr, int N) {
  __shared__ int cnt[64];
  __shared__ int cur[64];
  __shared__ int cstart[64];
  int t = threadIdx.x;
  int b = blockIdx.x;
  int estart = bbase[b], eend = bbase[b + 1];
  if (t < 64) cnt[t] = 0;
  __syncthreads();
  for (int e = estart + t; e < eend; e += 256)
    atomicAdd(&cnt[epack[e] >> 26], 1);
  __syncthreads();
  if (t == 0) {
    int run = estart;
    for (int i = 0; i < 64; ++i) { cur[i] = run; cstart[i] = run; run += cnt[i]; }
  }
  __syncthreads();
  if (t < 64) {
    int gn = b * 64 + t;
    if (gn < N) rowptr[gn] = cstart[t];
  }
  for (int e = estart + t; e < eend; e += 256) {
    unsigned pk = epack[e];
    int pos = atomicAdd(&cur[pk >> 26], 1);
    csr_src[pos] = (int)(pk & 0x3FFFFFFu);
  }
}

// ---------------- fused aggregation: one wave per dst node ------------------
template <int FINAL>
__global__ __launch_bounds__(256) void agg_kernel(
    const int* __restrict__ rowptr, const int* __restrict__ csr_src,
    const float* __restrict__ ssrc, const float* __restrict__ sdst,
    const halfT* __restrict__ Hin, const float* __restrict__ bias,
    const float* __restrict__ lw, const float* __restrict__ lb,
    float* __restrict__ out, int N) {
  __shared__ float4 pbuf[4][64];
  int wid = threadIdx.x >> 6;
  int n = blockIdx.x * 4 + wid;
  if (n >= N) return;
  int lane = threadIdx.x & 63;
  int head = lane >> 4;
  int base = rowptr[n];
  int deg = rowptr[n + 1] - base;
  float4 sd = ((const float4*)sdst)[n];
  const float* pb = (const float*)&pbuf[wid][0];

  float z0 = 0.f, z1 = 0.f, z2 = 0.f, z3 = 0.f;
  float ax = 0.f, ay = 0.f;

  for (int c = 0; c < deg; c += 64) {
    int i = c + lane;
    int sreg = 0;
    if (i < deg) {
      sreg = csr_src[base + i];
      float4 ss = ((const float4*)ssrc)[sreg];
      float e0 = ss.x + sd.x, e1 = ss.y + sd.y;
      float e2 = ss.z + sd.z, e3 = ss.w + sd.w;
      e0 = e0 > 0.f ? e0 : 0.2f * e0;
      e1 = e1 > 0.f ? e1 : 0.2f * e1;
      e2 = e2 > 0.f ? e2 : 0.2f * e2;
      e3 = e3 > 0.f ? e3 : 0.2f * e3;
      float p0 = __expf(e0), p1 = __expf(e1);
      float p2 = __expf(e2), p3 = __expf(e3);
      z0 += p0; z1 += p1; z2 += p2; z3 += p3;
      pbuf[wid][lane] = make_float4(p0, p1, p2, p3);
    }
    int cl = min(64, deg - c);
    int k = 0;
    for (; k + 4 <= cl; k += 4) {
      int s0 = __shfl(sreg, k);
      int s1 = __shfl(sreg, k + 1);
      int s2 = __shfl(sreg, k + 2);
      int s3 = __shfl(sreg, k + 3);
      f16x2 v0 = ((const f16x2*)(Hin + ((size_t)s0 << 7)))[lane];
      f16x2 v1 = ((const f16x2*)(Hin + ((size_t)s1 << 7)))[lane];
      f16x2 v2 = ((const f16x2*)(Hin + ((size_t)s2 << 7)))[lane];
      f16x2 v3 = ((const f16x2*)(Hin + ((size_t)s3 << 7)))[lane];
      float q0 = pb[k * 4 + head];
      float q1 = pb[(k + 1) * 4 + head];
      float q2 = pb[(k + 2) * 4 + head];
      float q3 = pb[(k + 3) * 4 + head];
      ax = fmaf(q0, (float)v0[0], ax); ay = fmaf(q0, (float)v0[1], ay);
      ax = fmaf(q1, (float)v1[0], ax); ay = fmaf(q1, (float)v1[1], ay);
      ax = fmaf(q2, (float)v2[0], ax); ay = fmaf(q2, (float)v2[1], ay);
      ax = fmaf(q3, (float)v3[0], ax); ay = fmaf(q3, (float)v3[1], ay);
    }
    for (; k < cl; ++k) {
      int s0 = __shfl(sreg, k);
      f16x2 v0 = ((const f16x2*)(Hin + ((size_t)s0 << 7)))[lane];
      float q0 = pb[k * 4 + head];
      ax = fmaf(q0, (float)v0[0], ax); ay = fmaf(q0, (float)v0[1], ay);
    }
  }

#pragma unroll
  for (int off = 32; off; off >>= 1) {
    z0 += __shfl_xor(z0, off);
    z1 += __shfl_xor(z1, off);
    z2 += __shfl_xor(z2, off);
    z3 += __shfl_xor(z3, off);
  }
  float zz = (head == 0) ? z0 : (head == 1) ? z1 : (head == 2) ? z2 : z3;
  float rz = 1.f / (zz + 1e-16f);
  float2 bb = ((const float2*)bias)[lane];
  float ox = fmaxf(fmaf(ax, rz, bb.x), 0.f);
  float oy = fmaxf(fmaf(ay, rz, bb.y), 0.f);

  if (FINAL) {
    float2 ww = ((const float2*)lw)[lane];
    float v = ox * ww.x + oy * ww.y;
#pragma unroll
    for (int off = 32; off; off >>= 1) v += __shfl_down(v, off);
    if (lane == 0) out[n] = v + lb[0];
  } else {
    ((f16x2*)out)[(size_t)n * 64 + lane] = (f16x2){(halfT)ox, (halfT)oy};
  }
}

extern "C" void kernel_launch(void* const* d_in, const int* in_sizes, int n_in,
                              void* d_out, int out_size, void* d_ws, size_t ws_size,
                              hipStream_t stream) {
  const float* x   = (const float*)d_in[0];
  const int*   src = (const int*)d_in[1];
  const int*   dst = (const int*)d_in[2];
  const float* W1  = (const float*)d_in[3];
  const float* as1 = (const float*)d_in[4];
  const float* ad1 = (const float*)d_in[5];
  const float* b1  = (const float*)d_in[6];
  const float* W2  = (const float*)d_in[7];
  const float* as2 = (const float*)d_in[8];
  const float* ad2 = (const float*)d_in[9];
  const float* b2  = (const float*)d_in[10];
  const float* lw  = (const float*)d_in[11];
  const float* lb  = (const float*)d_in[12];

  int N = in_sizes[0] / 128;
  int E = in_sizes[1];
  int Etot = E + N;
  int NB = (N + 63) / 64;
  int nb64 = (N + 63) / 64;
  int Npad = nb64 * 64;

  char* w = (char*)d_ws;
  halfT* x16  = (halfT*)w; w += (size_t)Npad * 128 * 2;
  halfT* h16  = (halfT*)w; w += (size_t)Npad * 128 * 2;
  halfT* xb16 = (halfT*)w; w += (size_t)Npad * 128 * 2;
  halfT* wf1  = (halfT*)w; w += 16384 * 2;
  halfT* wf2  = (halfT*)w; w += 16384 * 2;
  float* ssrc = (float*)w; w += (size_t)N * 4 * 4;
  float* sdst = (float*)w; w += (size_t)N * 4 * 4;
  int* bcnt   = (int*)w;   w += (MAXNB + 1) * 4;
  int* bbase  = (int*)w;   w += (MAXNB + 1) * 4;
  int* bcur   = (int*)w;   w += (MAXNB + 1) * 4;
  int* rowptr = (int*)w;   w += (size_t)(N + 1) * 4;
  unsigned* epack = (unsigned*)w; w += (size_t)Etot * 4;
  int* csr_src = (int*)w;  w += (size_t)Etot * 4;

  int cx_grid  = (N * 128 / 8 + 255) / 256;
  int sc_grid  = (Etot + SCHUNK - 1) / SCHUNK;
  int agg_grid = (N + 3) / 4;

  // ---- casts ----
  cast_x_kernel<<<cx_grid, 256, 0, stream>>>(x, x16, N * 128 / 8);
  cast_w_kernel<<<64, 256, 0, stream>>>(W1, wf1);
  cast_w_kernel<<<64, 256, 0, stream>>>(W2, wf2);

  // ---- CSR build via buckets (reused by both layers) ----
  hipMemsetAsync(bcnt, 0, (size_t)(MAXNB + 1) * 4, stream);
  hist64_kernel<<<512, 256, 0, stream>>>(dst, bcnt, Etot, E, NB);
  bscan_kernel<<<1, 256, 0, stream>>>(bcnt, bbase, bcur, rowptr, NB, Etot, N);
  scatter64_kernel<<<sc_grid, 256, 0, stream>>>(src, dst, bcur, epack, Etot, E, NB);
  bucket_sort_kernel<<<NB, 256, 0, stream>>>(epack, bbase, csr_src, rowptr, N);

  // ---- Layer 1 ----
  gemm_mfma_kernel<<<nb64, 256, 0, stream>>>(x16, wf1, as1, ad1, h16, ssrc, sdst, N);
  agg_kernel<0><<<agg_grid, 256, 0, stream>>>(rowptr, csr_src, ssrc, sdst, h16,
                                              b1, nullptr, nullptr, (float*)xb16, N);

  // ---- Layer 2 (fused final linear) ----
  gemm_mfma_kernel<<<nb64, 256, 0, stream>>>(xb16, wf2, as2, ad2, h16, ssrc, sdst, N);
  agg_kernel<1><<<agg_grid, 256, 0, stream>>>(rowptr, csr_src, ssrc, sdst, h16,
                                              b2, lw, lb, (float*)d_out, N);
}

// Round 9
// 179.681 us; speedup vs baseline: 8.9588x; 1.1425x over previous
//
#include <hip/hip_runtime.h>

// GAT 2-layer v8: v7 with SCHUNK 16384->4096 (scatter64 parallelism fix).
// fp16 rows + MFMA gemm + per-wave CSR gather agg; CSR via bucket-windowed
// scatter + per-bucket LDS counting sort.
// N=50000, E=800000 (+N self loops), H=4 heads, C=32, HC=128.

typedef float f32x4 __attribute__((ext_vector_type(4)));
typedef _Float16 f16x8 __attribute__((ext_vector_type(8)));
typedef _Float16 f16x2 __attribute__((ext_vector_type(2)));
typedef _Float16 halfT;

#define SCHUNK 4096
#define MAXNB 1024  // 64-node buckets; supports N <= 65536

// ---------------- casts -----------------------------------------------------
__global__ __launch_bounds__(256) void cast_x_kernel(
    const float* __restrict__ in, halfT* __restrict__ outp, int total8) {
  int i = blockIdx.x * 256 + threadIdx.x;
  if (i >= total8) return;
  f32x4 a = ((const f32x4*)in)[i * 2];
  f32x4 b = ((const f32x4*)in)[i * 2 + 1];
  f16x8 o;
  o[0] = (halfT)a.x; o[1] = (halfT)a.y; o[2] = (halfT)a.z; o[3] = (halfT)a.w;
  o[4] = (halfT)b.x; o[5] = (halfT)b.y; o[6] = (halfT)b.z; o[7] = (halfT)b.w;
  ((f16x8*)outp)[i] = o;
}

// W [128][128] fp32 -> B-fragment-ordered fp16
__global__ __launch_bounds__(256) void cast_w_kernel(
    const float* __restrict__ W, halfT* __restrict__ wf) {
  int idx = blockIdx.x * 256 + threadIdx.x;  // 0..16383
  int j = idx & 7, lane = (idx >> 3) & 63, ks = (idx >> 9) & 3, nt = idx >> 11;
  int k = ks * 32 + (lane >> 4) * 8 + j;
  int n = nt * 16 + (lane & 15);
  wf[idx] = (halfT)W[k * 128 + n];
}

// ------- MFMA GEMM + scores -------------------------------------------------
__global__ __launch_bounds__(256) void gemm_mfma_kernel(
    const halfT* __restrict__ Xh, const halfT* __restrict__ Wf,
    const float* __restrict__ a_src, const float* __restrict__ a_dst,
    halfT* __restrict__ Hh, float* __restrict__ ssrc, float* __restrict__ sdst,
    int N) {
  __shared__ f16x8 wlds[2048];
  __shared__ float cst[4][16][134];
  int t = threadIdx.x;
  for (int i = t; i < 2048; i += 256) wlds[i] = ((const f16x8*)Wf)[i];
  __syncthreads();

  int w = t >> 6, lane = t & 63;
  int growbase = blockIdx.x * 64 + w * 16;
  const f16x8* xrow =
      (const f16x8*)(Xh + (size_t)(growbase + (lane & 15)) * 128 + (lane >> 4) * 8);

  f32x4 acc[8];
#pragma unroll
  for (int nt = 0; nt < 8; ++nt) acc[nt] = (f32x4){0.f, 0.f, 0.f, 0.f};

#pragma unroll
  for (int ks = 0; ks < 4; ++ks) {
    f16x8 af = xrow[ks * 4];
#pragma unroll
    for (int nt = 0; nt < 8; ++nt)
      acc[nt] = __builtin_amdgcn_mfma_f32_16x16x32_f16(
          af, wlds[(nt * 4 + ks) * 64 + lane], acc[nt], 0, 0, 0);
  }

#pragma unroll
  for (int nt = 0; nt < 8; ++nt)
#pragma unroll
    for (int j = 0; j < 4; ++j)
      cst[w][(lane >> 4) * 4 + j][nt * 16 + (lane & 15)] = acc[nt][j];
  __syncthreads();

  int r = lane >> 2, q = lane & 3;
  int grow = growbase + r;
  if (grow >= N) return;
  const float* cp = &cst[w][r][q * 32];
  const float* asp = a_src + q * 32;
  const float* adp = a_dst + q * 32;
  f16x8* hp = (f16x8*)(Hh + (size_t)grow * 128 + q * 32);
  float ss = 0.f, sd = 0.f;
#pragma unroll
  for (int g = 0; g < 4; ++g) {
    f16x8 hv;
#pragma unroll
    for (int jj = 0; jj < 8; ++jj) {
      float v = cp[g * 8 + jj];
      ss = fmaf(v, asp[g * 8 + jj], ss);
      sd = fmaf(v, adp[g * 8 + jj], sd);
      hv[jj] = (halfT)v;
    }
    hp[g] = hv;
  }
  ssrc[grow * 4 + q] = ss;
  sdst[grow * 4 + q] = sd;
}

// ---------------- bucket build ----------------------------------------------
__global__ __launch_bounds__(256) void hist64_kernel(
    const int* __restrict__ dst, int* __restrict__ bcnt, int Etot, int E, int NB) {
  __shared__ int h[MAXNB];
  for (int i = threadIdx.x; i < NB; i += 256) h[i] = 0;
  __syncthreads();
  for (int e = blockIdx.x * 256 + threadIdx.x; e < Etot; e += gridDim.x * 256) {
    int d = (e < E) ? dst[e] : (e - E);
    atomicAdd(&h[d >> 6], 1);
  }
  __syncthreads();
  for (int i = threadIdx.x; i < NB; i += 256)
    if (h[i]) atomicAdd(&bcnt[i], h[i]);
}

__global__ __launch_bounds__(256) void bscan_kernel(
    const int* __restrict__ bcnt, int* __restrict__ bbase,
    int* __restrict__ bcur, int* __restrict__ rowptr, int NB, int Etot, int N) {
  __shared__ int tsum[256];
  int t = threadIdx.x;
  int v[4];
  int s = 0;
#pragma unroll
  for (int j = 0; j < 4; ++j) {
    int i = t * 4 + j;
    v[j] = (i < NB) ? bcnt[i] : 0;
    s += v[j];
  }
  tsum[t] = s;
  __syncthreads();
  for (int off = 1; off < 256; off <<= 1) {
    int u = (t >= off) ? tsum[t - off] : 0;
    __syncthreads();
    tsum[t] += u;
    __syncthreads();
  }
  int run = tsum[t] - s;
#pragma unroll
  for (int j = 0; j < 4; ++j) {
    int i = t * 4 + j;
    if (i < NB) { bbase[i] = run; bcur[i] = run; }
    run += v[j];
  }
  if (t == 0) { bbase[NB] = Etot; rowptr[N] = Etot; }
}

// bucket-windowed scatter: block-exclusive contiguous runs per (block,bucket)
__global__ __launch_bounds__(256) void scatter64_kernel(
    const int* __restrict__ src, const int* __restrict__ dst,
    int* __restrict__ bcur, unsigned* __restrict__ epack,
    int Etot, int E, int NB) {
  __shared__ int h[MAXNB];
  __shared__ int cur[MAXNB];
  int t = threadIdx.x;
  int e0 = blockIdx.x * SCHUNK;
  int e1 = min(e0 + SCHUNK, Etot);
  for (int i = t; i < NB; i += 256) h[i] = 0;
  __syncthreads();
  for (int e = e0 + t; e < e1; e += 256) {
    int d = (e < E) ? dst[e] : (e - E);
    atomicAdd(&h[d >> 6], 1);
  }
  __syncthreads();
  for (int i = t; i < NB; i += 256) {
    int c = h[i];
    cur[i] = c ? atomicAdd(&bcur[i], c) : 0;
  }
  __syncthreads();
  for (int e = e0 + t; e < e1; e += 256) {
    int s = (e < E) ? src[e] : (e - E);
    int d = (e < E) ? dst[e] : (e - E);
    int b = d >> 6;
    int pos = atomicAdd(&cur[b], 1);
    epack[pos] = ((unsigned)(d & 63) << 26) | (unsigned)s;
  }
}

// per-bucket counting sort: epack window -> node-grouped csr_src + rowptr.
// cstart[] snapshots the scan so rowptr publication can't race cur[] (R6 bug).
__global__ __launch_bounds__(256) void bucket_sort_kernel(
    const unsigned* __restrict__ epack, const int* __restrict__ bbase,
    int* __restrict__ csr_src, int* __restrict__ rowptr, int N) {
  __shared__ int cnt[64];
  __shared__ int cur[64];
  __shared__ int cstart[64];
  int t = threadIdx.x;
  int b = blockIdx.x;
  int estart = bbase[b], eend = bbase[b + 1];
  if (t < 64) cnt[t] = 0;
  __syncthreads();
  for (int e = estart + t; e < eend; e += 256)
    atomicAdd(&cnt[epack[e] >> 26], 1);
  __syncthreads();
  if (t == 0) {
    int run = estart;
    for (int i = 0; i < 64; ++i) { cur[i] = run; cstart[i] = run; run += cnt[i]; }
  }
  __syncthreads();
  if (t < 64) {
    int gn = b * 64 + t;
    if (gn < N) rowptr[gn] = cstart[t];
  }
  for (int e = estart + t; e < eend; e += 256) {
    unsigned pk = epack[e];
    int pos = atomicAdd(&cur[pk >> 26], 1);
    csr_src[pos] = (int)(pk & 0x3FFFFFFu);
  }
}

// ---------------- fused aggregation: one wave per dst node ------------------
template <int FINAL>
__global__ __launch_bounds__(256) void agg_kernel(
    const int* __restrict__ rowptr, const int* __restrict__ csr_src,
    const float* __restrict__ ssrc, const float* __restrict__ sdst,
    const halfT* __restrict__ Hin, const float* __restrict__ bias,
    const float* __restrict__ lw, const float* __restrict__ lb,
    float* __restrict__ out, int N) {
  __shared__ float4 pbuf[4][64];
  int wid = threadIdx.x >> 6;
  int n = blockIdx.x * 4 + wid;
  if (n >= N) return;
  int lane = threadIdx.x & 63;
  int head = lane >> 4;
  int base = rowptr[n];
  int deg = rowptr[n + 1] - base;
  float4 sd = ((const float4*)sdst)[n];
  const float* pb = (const float*)&pbuf[wid][0];

  float z0 = 0.f, z1 = 0.f, z2 = 0.f, z3 = 0.f;
  float ax = 0.f, ay = 0.f;

  for (int c = 0; c < deg; c += 64) {
    int i = c + lane;
    int sreg = 0;
    if (i < deg) {
      sreg = csr_src[base + i];
      float4 ss = ((const float4*)ssrc)[sreg];
      float e0 = ss.x + sd.x, e1 = ss.y + sd.y;
      float e2 = ss.z + sd.z, e3 = ss.w + sd.w;
      e0 = e0 > 0.f ? e0 : 0.2f * e0;
      e1 = e1 > 0.f ? e1 : 0.2f * e1;
      e2 = e2 > 0.f ? e2 : 0.2f * e2;
      e3 = e3 > 0.f ? e3 : 0.2f * e3;
      float p0 = __expf(e0), p1 = __expf(e1);
      float p2 = __expf(e2), p3 = __expf(e3);
      z0 += p0; z1 += p1; z2 += p2; z3 += p3;
      pbuf[wid][lane] = make_float4(p0, p1, p2, p3);
    }
    int cl = min(64, deg - c);
    int k = 0;
    for (; k + 4 <= cl; k += 4) {
      int s0 = __shfl(sreg, k);
      int s1 = __shfl(sreg, k + 1);
      int s2 = __shfl(sreg, k + 2);
      int s3 = __shfl(sreg, k + 3);
      f16x2 v0 = ((const f16x2*)(Hin + ((size_t)s0 << 7)))[lane];
      f16x2 v1 = ((const f16x2*)(Hin + ((size_t)s1 << 7)))[lane];
      f16x2 v2 = ((const f16x2*)(Hin + ((size_t)s2 << 7)))[lane];
      f16x2 v3 = ((const f16x2*)(Hin + ((size_t)s3 << 7)))[lane];
      float q0 = pb[k * 4 + head];
      float q1 = pb[(k + 1) * 4 + head];
      float q2 = pb[(k + 2) * 4 + head];
      float q3 = pb[(k + 3) * 4 + head];
      ax = fmaf(q0, (float)v0[0], ax); ay = fmaf(q0, (float)v0[1], ay);
      ax = fmaf(q1, (float)v1[0], ax); ay = fmaf(q1, (float)v1[1], ay);
      ax = fmaf(q2, (float)v2[0], ax); ay = fmaf(q2, (float)v2[1], ay);
      ax = fmaf(q3, (float)v3[0], ax); ay = fmaf(q3, (float)v3[1], ay);
    }
    for (; k < cl; ++k) {
      int s0 = __shfl(sreg, k);
      f16x2 v0 = ((const f16x2*)(Hin + ((size_t)s0 << 7)))[lane];
      float q0 = pb[k * 4 + head];
      ax = fmaf(q0, (float)v0[0], ax); ay = fmaf(q0, (float)v0[1], ay);
    }
  }

#pragma unroll
  for (int off = 32; off; off >>= 1) {
    z0 += __shfl_xor(z0, off);
    z1 += __shfl_xor(z1, off);
    z2 += __shfl_xor(z2, off);
    z3 += __shfl_xor(z3, off);
  }
  float zz = (head == 0) ? z0 : (head == 1) ? z1 : (head == 2) ? z2 : z3;
  float rz = 1.f / (zz + 1e-16f);
  float2 bb = ((const float2*)bias)[lane];
  float ox = fmaxf(fmaf(ax, rz, bb.x), 0.f);
  float oy = fmaxf(fmaf(ay, rz, bb.y), 0.f);

  if (FINAL) {
    float2 ww = ((const float2*)lw)[lane];
    float v = ox * ww.x + oy * ww.y;
#pragma unroll
    for (int off = 32; off; off >>= 1) v += __shfl_down(v, off);
    if (lane == 0) out[n] = v + lb[0];
  } else {
    ((f16x2*)out)[(size_t)n * 64 + lane] = (f16x2){(halfT)ox, (halfT)oy};
  }
}

extern "C" void kernel_launch(void* const* d_in, const int* in_sizes, int n_in,
                              void* d_out, int out_size, void* d_ws, size_t ws_size,
                              hipStream_t stream) {
  const float* x   = (const float*)d_in[0];
  const int*   src = (const int*)d_in[1];
  const int*   dst = (const int*)d_in[2];
  const float* W1  = (const float*)d_in[3];
  const float* as1 = (const float*)d_in[4];
  const float* ad1 = (const float*)d_in[5];
  const float* b1  = (const float*)d_in[6];
  const float* W2  = (const float*)d_in[7];
  const float* as2 = (const float*)d_in[8];
  const float* ad2 = (const float*)d_in[9];
  const float* b2  = (const float*)d_in[10];
  const float* lw  = (const float*)d_in[11];
  const float* lb  = (const float*)d_in[12];

  int N = in_sizes[0] / 128;
  int E = in_sizes[1];
  int Etot = E + N;
  int NB = (N + 63) / 64;
  int nb64 = (N + 63) / 64;
  int Npad = nb64 * 64;

  char* w = (char*)d_ws;
  halfT* x16  = (halfT*)w; w += (size_t)Npad * 128 * 2;
  halfT* h16  = (halfT*)w; w += (size_t)Npad * 128 * 2;
  halfT* xb16 = (halfT*)w; w += (size_t)Npad * 128 * 2;
  halfT* wf1  = (halfT*)w; w += 16384 * 2;
  halfT* wf2  = (halfT*)w; w += 16384 * 2;
  float* ssrc = (float*)w; w += (size_t)N * 4 * 4;
  float* sdst = (float*)w; w += (size_t)N * 4 * 4;
  int* bcnt   = (int*)w;   w += (MAXNB + 1) * 4;
  int* bbase  = (int*)w;   w += (MAXNB + 1) * 4;
  int* bcur   = (int*)w;   w += (MAXNB + 1) * 4;
  int* rowptr = (int*)w;   w += (size_t)(N + 1) * 4;
  unsigned* epack = (unsigned*)w; w += (size_t)Etot * 4;
  int* csr_src = (int*)w;  w += (size_t)Etot * 4;

  int cx_grid  = (N * 128 / 8 + 255) / 256;
  int sc_grid  = (Etot + SCHUNK - 1) / SCHUNK;
  int agg_grid = (N + 3) / 4;

  // ---- casts ----
  cast_x_kernel<<<cx_grid, 256, 0, stream>>>(x, x16, N * 128 / 8);
  cast_w_kernel<<<64, 256, 0, stream>>>(W1, wf1);
  cast_w_kernel<<<64, 256, 0, stream>>>(W2, wf2);

  // ---- CSR build via buckets (reused by both layers) ----
  hipMemsetAsync(bcnt, 0, (size_t)(MAXNB + 1) * 4, stream);
  hist64_kernel<<<512, 256, 0, stream>>>(dst, bcnt, Etot, E, NB);
  bscan_kernel<<<1, 256, 0, stream>>>(bcnt, bbase, bcur, rowptr, NB, Etot, N);
  scatter64_kernel<<<sc_grid, 256, 0, stream>>>(src, dst, bcur, epack, Etot, E, NB);
  bucket_sort_kernel<<<NB, 256, 0, stream>>>(epack, bbase, csr_src, rowptr, N);

  // ---- Layer 1 ----
  gemm_mfma_kernel<<<nb64, 256, 0, stream>>>(x16, wf1, as1, ad1, h16, ssrc, sdst, N);
  agg_kernel<0><<<agg_grid, 256, 0, stream>>>(rowptr, csr_src, ssrc, sdst, h16,
                                              b1, nullptr, nullptr, (float*)xb16, N);

  // ---- Layer 2 (fused final linear) ----
  gemm_mfma_kernel<<<nb64, 256, 0, stream>>>(xb16, wf2, as2, ad2, h16, ssrc, sdst, N);
  agg_kernel<1><<<agg_grid, 256, 0, stream>>>(rowptr, csr_src, ssrc, sdst, h16,
                                              b2, lw, lb, (float*)d_out, N);
}

// Round 10
// 170.729 us; speedup vs baseline: 9.4285x; 1.0524x over previous
//
#include <hip/hip_runtime.h>

// GAT 2-layer v9: gemm fuses x-cast + 128-rows/block; agg unroll-8.
// fp16 rows + MFMA gemm + per-wave CSR gather agg; CSR via bucket-windowed
// scatter + per-bucket LDS counting sort.
// N=50000, E=800000 (+N self loops), H=4 heads, C=32, HC=128.

typedef float f32x4 __attribute__((ext_vector_type(4)));
typedef _Float16 f16x8 __attribute__((ext_vector_type(8)));
typedef _Float16 f16x2 __attribute__((ext_vector_type(2)));
typedef _Float16 halfT;

#define SCHUNK 4096
#define MAXNB 1024  // 64-node buckets; supports N <= 65536

// W [128][128] fp32 -> B-fragment-ordered fp16
__global__ __launch_bounds__(256) void cast_w_kernel(
    const float* __restrict__ W, halfT* __restrict__ wf) {
  int idx = blockIdx.x * 256 + threadIdx.x;  // 0..16383
  int j = idx & 7, lane = (idx >> 3) & 63, ks = (idx >> 9) & 3, nt = idx >> 11;
  int k = ks * 32 + (lane >> 4) * 8 + j;
  int n = nt * 16 + (lane & 15);
  wf[idx] = (halfT)W[k * 128 + n];
}

// ------- MFMA GEMM + scores: 128 rows/block (2 tiles), optional fp32-A cast
template <int CAST>
__global__ __launch_bounds__(256) void gemm_mfma_kernel(
    const float* __restrict__ Xf, const halfT* __restrict__ Xh,
    const halfT* __restrict__ Wf,
    const float* __restrict__ a_src, const float* __restrict__ a_dst,
    halfT* __restrict__ Hh, float* __restrict__ ssrc, float* __restrict__ sdst,
    int N) {
  __shared__ f16x8 wlds[2048];
  __shared__ float cst[4][16][134];
  int t = threadIdx.x;
  for (int i = t; i < 2048; i += 256) wlds[i] = ((const f16x8*)Wf)[i];
  __syncthreads();

  int w = t >> 6, lane = t & 63;

  for (int tile = 0; tile < 2; ++tile) {
    int growbase = blockIdx.x * 128 + tile * 64 + w * 16;
    int arow = growbase + (lane & 15);
    if (arow > N - 1) arow = N - 1;  // clamp: no OOB reads on input

    f32x4 acc[8];
#pragma unroll
    for (int nt = 0; nt < 8; ++nt) acc[nt] = (f32x4){0.f, 0.f, 0.f, 0.f};

#pragma unroll
    for (int ks = 0; ks < 4; ++ks) {
      f16x8 af;
      if (CAST) {
        const f32x4* xr = (const f32x4*)(Xf + (size_t)arow * 128 + (lane >> 4) * 8);
        f32x4 a = xr[ks * 8];
        f32x4 b = xr[ks * 8 + 1];
        af[0] = (halfT)a.x; af[1] = (halfT)a.y; af[2] = (halfT)a.z; af[3] = (halfT)a.w;
        af[4] = (halfT)b.x; af[5] = (halfT)b.y; af[6] = (halfT)b.z; af[7] = (halfT)b.w;
      } else {
        const f16x8* xr = (const f16x8*)(Xh + (size_t)arow * 128 + (lane >> 4) * 8);
        af = xr[ks * 4];
      }
#pragma unroll
      for (int nt = 0; nt < 8; ++nt)
        acc[nt] = __builtin_amdgcn_mfma_f32_16x16x32_f16(
            af, wlds[(nt * 4 + ks) * 64 + lane], acc[nt], 0, 0, 0);
    }

#pragma unroll
    for (int nt = 0; nt < 8; ++nt)
#pragma unroll
      for (int j = 0; j < 4; ++j)
        cst[w][(lane >> 4) * 4 + j][nt * 16 + (lane & 15)] = acc[nt][j];
    __syncthreads();

    int r = lane >> 2, q = lane & 3;
    int grow = growbase + r;
    if (grow < N) {
      const float* cp = &cst[w][r][q * 32];
      const float* asp = a_src + q * 32;
      const float* adp = a_dst + q * 32;
      f16x8* hp = (f16x8*)(Hh + (size_t)grow * 128 + q * 32);
      float ss = 0.f, sd = 0.f;
#pragma unroll
      for (int g = 0; g < 4; ++g) {
        f16x8 hv;
#pragma unroll
        for (int jj = 0; jj < 8; ++jj) {
          float v = cp[g * 8 + jj];
          ss = fmaf(v, asp[g * 8 + jj], ss);
          sd = fmaf(v, adp[g * 8 + jj], sd);
          hv[jj] = (halfT)v;
        }
        hp[g] = hv;
      }
      ssrc[grow * 4 + q] = ss;
      sdst[grow * 4 + q] = sd;
    }
    __syncthreads();
  }
}

// ---------------- bucket build ----------------------------------------------
__global__ __launch_bounds__(256) void hist64_kernel(
    const int* __restrict__ dst, int* __restrict__ bcnt, int Etot, int E, int NB) {
  __shared__ int h[MAXNB];
  for (int i = threadIdx.x; i < NB; i += 256) h[i] = 0;
  __syncthreads();
  for (int e = blockIdx.x * 256 + threadIdx.x; e < Etot; e += gridDim.x * 256) {
    int d = (e < E) ? dst[e] : (e - E);
    atomicAdd(&h[d >> 6], 1);
  }
  __syncthreads();
  for (int i = threadIdx.x; i < NB; i += 256)
    if (h[i]) atomicAdd(&bcnt[i], h[i]);
}

__global__ __launch_bounds__(256) void bscan_kernel(
    const int* __restrict__ bcnt, int* __restrict__ bbase,
    int* __restrict__ bcur, int* __restrict__ rowptr, int NB, int Etot, int N) {
  __shared__ int tsum[256];
  int t = threadIdx.x;
  int v[4];
  int s = 0;
#pragma unroll
  for (int j = 0; j < 4; ++j) {
    int i = t * 4 + j;
    v[j] = (i < NB) ? bcnt[i] : 0;
    s += v[j];
  }
  tsum[t] = s;
  __syncthreads();
  for (int off = 1; off < 256; off <<= 1) {
    int u = (t >= off) ? tsum[t - off] : 0;
    __syncthreads();
    tsum[t] += u;
    __syncthreads();
  }
  int run = tsum[t] - s;
#pragma unroll
  for (int j = 0; j < 4; ++j) {
    int i = t * 4 + j;
    if (i < NB) { bbase[i] = run; bcur[i] = run; }
    run += v[j];
  }
  if (t == 0) { bbase[NB] = Etot; rowptr[N] = Etot; }
}

// bucket-windowed scatter: block-exclusive contiguous runs per (block,bucket)
__global__ __launch_bounds__(256) void scatter64_kernel(
    const int* __restrict__ src, const int* __restrict__ dst,
    int* __restrict__ bcur, unsigned* __restrict__ epack,
    int Etot, int E, int NB) {
  __shared__ int h[MAXNB];
  __shared__ int cur[MAXNB];
  int t = threadIdx.x;
  int e0 = blockIdx.x * SCHUNK;
  int e1 = min(e0 + SCHUNK, Etot);
  for (int i = t; i < NB; i += 256) h[i] = 0;
  __syncthreads();
  for (int e = e0 + t; e < e1; e += 256) {
    int d = (e < E) ? dst[e] : (e - E);
    atomicAdd(&h[d >> 6], 1);
  }
  __syncthreads();
  for (int i = t; i < NB; i += 256) {
    int c = h[i];
    cur[i] = c ? atomicAdd(&bcur[i], c) : 0;
  }
  __syncthreads();
  for (int e = e0 + t; e < e1; e += 256) {
    int s = (e < E) ? src[e] : (e - E);
    int d = (e < E) ? dst[e] : (e - E);
    int b = d >> 6;
    int pos = atomicAdd(&cur[b], 1);
    epack[pos] = ((unsigned)(d & 63) << 26) | (unsigned)s;
  }
}

// per-bucket counting sort: epack window -> node-grouped csr_src + rowptr.
// cstart[] snapshots the scan so rowptr publication can't race cur[] (R6 bug).
__global__ __launch_bounds__(256) void bucket_sort_kernel(
    const unsigned* __restrict__ epack, const int* __restrict__ bbase,
    int* __restrict__ csr_src, int* __restrict__ rowptr, int N) {
  __shared__ int cnt[64];
  __shared__ int cur[64];
  __shared__ int cstart[64];
  int t = threadIdx.x;
  int b = blockIdx.x;
  int estart = bbase[b], eend = bbase[b + 1];
  if (t < 64) cnt[t] = 0;
  __syncthreads();
  for (int e = estart + t; e < eend; e += 256)
    atomicAdd(&cnt[epack[e] >> 26], 1);
  __syncthreads();
  if (t == 0) {
    int run = estart;
    for (int i = 0; i < 64; ++i) { cur[i] = run; cstart[i] = run; run += cnt[i]; }
  }
  __syncthreads();
  if (t < 64) {
    int gn = b * 64 + t;
    if (gn < N) rowptr[gn] = cstart[t];
  }
  for (int e = estart + t; e < eend; e += 256) {
    unsigned pk = epack[e];
    int pos = atomicAdd(&cur[pk >> 26], 1);
    csr_src[pos] = (int)(pk & 0x3FFFFFFu);
  }
}

// ---------------- fused aggregation: one wave per dst node, unroll-8 --------
template <int FINAL>
__global__ __launch_bounds__(256) void agg_kernel(
    const int* __restrict__ rowptr, const int* __restrict__ csr_src,
    const float* __restrict__ ssrc, const float* __restrict__ sdst,
    const halfT* __restrict__ Hin, const float* __restrict__ bias,
    const float* __restrict__ lw, const float* __restrict__ lb,
    float* __restrict__ out, int N) {
  __shared__ float4 pbuf[4][64];
  int wid = threadIdx.x >> 6;
  int n = blockIdx.x * 4 + wid;
  if (n >= N) return;
  int lane = threadIdx.x & 63;
  int head = lane >> 4;
  int base = rowptr[n];
  int deg = rowptr[n + 1] - base;
  float4 sd = ((const float4*)sdst)[n];
  const float* pb = (const float*)&pbuf[wid][0];

  float z0 = 0.f, z1 = 0.f, z2 = 0.f, z3 = 0.f;
  float ax = 0.f, ay = 0.f;

  for (int c = 0; c < deg; c += 64) {
    int i = c + lane;
    int sreg = 0;
    if (i < deg) {
      sreg = csr_src[base + i];
      float4 ss = ((const float4*)ssrc)[sreg];
      float e0 = ss.x + sd.x, e1 = ss.y + sd.y;
      float e2 = ss.z + sd.z, e3 = ss.w + sd.w;
      e0 = e0 > 0.f ? e0 : 0.2f * e0;
      e1 = e1 > 0.f ? e1 : 0.2f * e1;
      e2 = e2 > 0.f ? e2 : 0.2f * e2;
      e3 = e3 > 0.f ? e3 : 0.2f * e3;
      float p0 = __expf(e0), p1 = __expf(e1);
      float p2 = __expf(e2), p3 = __expf(e3);
      z0 += p0; z1 += p1; z2 += p2; z3 += p3;
      pbuf[wid][lane] = make_float4(p0, p1, p2, p3);
    }
    int cl = min(64, deg - c);
    int k = 0;
    for (; k + 8 <= cl; k += 8) {
      int sA[8];
      f16x2 vA[8];
#pragma unroll
      for (int u = 0; u < 8; ++u) sA[u] = __shfl(sreg, k + u);
#pragma unroll
      for (int u = 0; u < 8; ++u)
        vA[u] = ((const f16x2*)(Hin + ((size_t)sA[u] << 7)))[lane];
#pragma unroll
      for (int u = 0; u < 8; ++u) {
        float q = pb[(k + u) * 4 + head];
        ax = fmaf(q, (float)vA[u][0], ax);
        ay = fmaf(q, (float)vA[u][1], ay);
      }
    }
    for (; k + 4 <= cl; k += 4) {
      int s0 = __shfl(sreg, k);
      int s1 = __shfl(sreg, k + 1);
      int s2 = __shfl(sreg, k + 2);
      int s3 = __shfl(sreg, k + 3);
      f16x2 v0 = ((const f16x2*)(Hin + ((size_t)s0 << 7)))[lane];
      f16x2 v1 = ((const f16x2*)(Hin + ((size_t)s1 << 7)))[lane];
      f16x2 v2 = ((const f16x2*)(Hin + ((size_t)s2 << 7)))[lane];
      f16x2 v3 = ((const f16x2*)(Hin + ((size_t)s3 << 7)))[lane];
      float q0 = pb[k * 4 + head];
      float q1 = pb[(k + 1) * 4 + head];
      float q2 = pb[(k + 2) * 4 + head];
      float q3 = pb[(k + 3) * 4 + head];
      ax = fmaf(q0, (float)v0[0], ax); ay = fmaf(q0, (float)v0[1], ay);
      ax = fmaf(q1, (float)v1[0], ax); ay = fmaf(q1, (float)v1[1], ay);
      ax = fmaf(q2, (float)v2[0], ax); ay = fmaf(q2, (float)v2[1], ay);
      ax = fmaf(q3, (float)v3[0], ax); ay = fmaf(q3, (float)v3[1], ay);
    }
    for (; k < cl; ++k) {
      int s0 = __shfl(sreg, k);
      f16x2 v0 = ((const f16x2*)(Hin + ((size_t)s0 << 7)))[lane];
      float q0 = pb[k * 4 + head];
      ax = fmaf(q0, (float)v0[0], ax); ay = fmaf(q0, (float)v0[1], ay);
    }
  }

#pragma unroll
  for (int off = 32; off; off >>= 1) {
    z0 += __shfl_xor(z0, off);
    z1 += __shfl_xor(z1, off);
    z2 += __shfl_xor(z2, off);
    z3 += __shfl_xor(z3, off);
  }
  float zz = (head == 0) ? z0 : (head == 1) ? z1 : (head == 2) ? z2 : z3;
  float rz = 1.f / (zz + 1e-16f);
  float2 bb = ((const float2*)bias)[lane];
  float ox = fmaxf(fmaf(ax, rz, bb.x), 0.f);
  float oy = fmaxf(fmaf(ay, rz, bb.y), 0.f);

  if (FINAL) {
    float2 ww = ((const float2*)lw)[lane];
    float v = ox * ww.x + oy * ww.y;
#pragma unroll
    for (int off = 32; off; off >>= 1) v += __shfl_down(v, off);
    if (lane == 0) out[n] = v + lb[0];
  } else {
    ((f16x2*)out)[(size_t)n * 64 + lane] = (f16x2){(halfT)ox, (halfT)oy};
  }
}

extern "C" void kernel_launch(void* const* d_in, const int* in_sizes, int n_in,
                              void* d_out, int out_size, void* d_ws, size_t ws_size,
                              hipStream_t stream) {
  const float* x   = (const float*)d_in[0];
  const int*   src = (const int*)d_in[1];
  const int*   dst = (const int*)d_in[2];
  const float* W1  = (const float*)d_in[3];
  const float* as1 = (const float*)d_in[4];
  const float* ad1 = (const float*)d_in[5];
  const float* b1  = (const float*)d_in[6];
  const float* W2  = (const float*)d_in[7];
  const float* as2 = (const float*)d_in[8];
  const float* ad2 = (const float*)d_in[9];
  const float* b2  = (const float*)d_in[10];
  const float* lw  = (const float*)d_in[11];
  const float* lb  = (const float*)d_in[12];

  int N = in_sizes[0] / 128;
  int E = in_sizes[1];
  int Etot = E + N;
  int NB = (N + 63) / 64;
  int nb128 = (N + 127) / 128;
  int Npad = nb128 * 128;

  char* w = (char*)d_ws;
  halfT* h16  = (halfT*)w; w += (size_t)Npad * 128 * 2;
  halfT* xb16 = (halfT*)w; w += (size_t)Npad * 128 * 2;
  halfT* wf1  = (halfT*)w; w += 16384 * 2;
  halfT* wf2  = (halfT*)w; w += 16384 * 2;
  float* ssrc = (float*)w; w += (size_t)N * 4 * 4;
  float* sdst = (float*)w; w += (size_t)N * 4 * 4;
  int* bcnt   = (int*)w;   w += (MAXNB + 1) * 4;
  int* bbase  = (int*)w;   w += (MAXNB + 1) * 4;
  int* bcur   = (int*)w;   w += (MAXNB + 1) * 4;
  int* rowptr = (int*)w;   w += (size_t)(N + 1) * 4;
  unsigned* epack = (unsigned*)w; w += (size_t)Etot * 4;
  int* csr_src = (int*)w;  w += (size_t)Etot * 4;

  int sc_grid  = (Etot + SCHUNK - 1) / SCHUNK;
  int agg_grid = (N + 3) / 4;

  // ---- W casts ----
  cast_w_kernel<<<64, 256, 0, stream>>>(W1, wf1);
  cast_w_kernel<<<64, 256, 0, stream>>>(W2, wf2);

  // ---- CSR build via buckets (reused by both layers) ----
  hipMemsetAsync(bcnt, 0, (size_t)(MAXNB + 1) * 4, stream);
  hist64_kernel<<<512, 256, 0, stream>>>(dst, bcnt, Etot, E, NB);
  bscan_kernel<<<1, 256, 0, stream>>>(bcnt, bbase, bcur, rowptr, NB, Etot, N);
  scatter64_kernel<<<sc_grid, 256, 0, stream>>>(src, dst, bcur, epack, Etot, E, NB);
  bucket_sort_kernel<<<NB, 256, 0, stream>>>(epack, bbase, csr_src, rowptr, N);

  // ---- Layer 1 (gemm reads fp32 x directly, casts in-register) ----
  gemm_mfma_kernel<1><<<nb128, 256, 0, stream>>>(x, nullptr, wf1, as1, ad1,
                                                 h16, ssrc, sdst, N);
  agg_kernel<0><<<agg_grid, 256, 0, stream>>>(rowptr, csr_src, ssrc, sdst, h16,
                                              b1, nullptr, nullptr, (float*)xb16, N);

  // ---- Layer 2 (fused final linear) ----
  gemm_mfma_kernel<0><<<nb128, 256, 0, stream>>>(nullptr, xb16, wf2, as2, ad2,
                                                 h16, ssrc, sdst, N);
  agg_kernel<1><<<agg_grid, 256, 0, stream>>>(rowptr, csr_src, ssrc, sdst, h16,
                                              b2, lw, lb, (float*)d_out, N);
}

// Round 11
// 149.404 us; speedup vs baseline: 10.7743x; 1.1427x over previous
//
#include <hip/hip_runtime.h>

// GAT 2-layer v10: fixed-capacity bucket windows (no hist/scan/memset),
// fused prep kernel, int2 rowinfo. 7 dispatches total.
// fp16 rows + MFMA gemm + per-wave CSR gather agg (BW-bound, at floor).
// N=50000, E=800000 (+N self loops), H=4 heads, C=32, HC=128.

typedef float f32x4 __attribute__((ext_vector_type(4)));
typedef _Float16 f16x8 __attribute__((ext_vector_type(8)));
typedef _Float16 f16x2 __attribute__((ext_vector_type(2)));
typedef _Float16 halfT;

#define SCHUNK 4096
#define MAXNB 1024   // 64-node buckets; supports N <= 65536
#define BCAP 2048    // slots per bucket window (expected ~1088, 29-sigma margin)

// ---- prep: cast W1+W2 to B-fragment order fp16; zero bucket cursors --------
__global__ __launch_bounds__(256) void prep_kernel(
    const float* __restrict__ W1, const float* __restrict__ W2,
    halfT* __restrict__ wf1, halfT* __restrict__ wf2, int* __restrict__ bcur) {
  int b = blockIdx.x;
  if (b < 128) {
    int idx = b * 256 + threadIdx.x;  // 0..32767
    const float* W = (idx < 16384) ? W1 : W2;
    halfT* wf = (idx < 16384) ? wf1 : wf2;
    int i = idx & 16383;
    int j = i & 7, lane = (i >> 3) & 63, ks = (i >> 9) & 3, nt = i >> 11;
    int k = ks * 32 + (lane >> 4) * 8 + j;
    int n = nt * 16 + (lane & 15);
    wf[i] = (halfT)W[k * 128 + n];
  } else {
    for (int i = threadIdx.x; i < MAXNB; i += 256) bcur[i] = 0;
  }
}

// ------- MFMA GEMM + scores: 128 rows/block (2 tiles), optional fp32-A cast
template <int CAST>
__global__ __launch_bounds__(256) void gemm_mfma_kernel(
    const float* __restrict__ Xf, const halfT* __restrict__ Xh,
    const halfT* __restrict__ Wf,
    const float* __restrict__ a_src, const float* __restrict__ a_dst,
    halfT* __restrict__ Hh, float* __restrict__ ssrc, float* __restrict__ sdst,
    int N) {
  __shared__ f16x8 wlds[2048];
  __shared__ float cst[4][16][134];
  int t = threadIdx.x;
  for (int i = t; i < 2048; i += 256) wlds[i] = ((const f16x8*)Wf)[i];
  __syncthreads();

  int w = t >> 6, lane = t & 63;

  for (int tile = 0; tile < 2; ++tile) {
    int growbase = blockIdx.x * 128 + tile * 64 + w * 16;
    int arow = growbase + (lane & 15);
    if (arow > N - 1) arow = N - 1;  // clamp: no OOB reads

    f32x4 acc[8];
#pragma unroll
    for (int nt = 0; nt < 8; ++nt) acc[nt] = (f32x4){0.f, 0.f, 0.f, 0.f};

#pragma unroll
    for (int ks = 0; ks < 4; ++ks) {
      f16x8 af;
      if (CAST) {
        const f32x4* xr = (const f32x4*)(Xf + (size_t)arow * 128 + (lane >> 4) * 8);
        f32x4 a = xr[ks * 8];
        f32x4 b = xr[ks * 8 + 1];
        af[0] = (halfT)a.x; af[1] = (halfT)a.y; af[2] = (halfT)a.z; af[3] = (halfT)a.w;
        af[4] = (halfT)b.x; af[5] = (halfT)b.y; af[6] = (halfT)b.z; af[7] = (halfT)b.w;
      } else {
        const f16x8* xr = (const f16x8*)(Xh + (size_t)arow * 128 + (lane >> 4) * 8);
        af = xr[ks * 4];
      }
#pragma unroll
      for (int nt = 0; nt < 8; ++nt)
        acc[nt] = __builtin_amdgcn_mfma_f32_16x16x32_f16(
            af, wlds[(nt * 4 + ks) * 64 + lane], acc[nt], 0, 0, 0);
    }

#pragma unroll
    for (int nt = 0; nt < 8; ++nt)
#pragma unroll
      for (int j = 0; j < 4; ++j)
        cst[w][(lane >> 4) * 4 + j][nt * 16 + (lane & 15)] = acc[nt][j];
    __syncthreads();

    int r = lane >> 2, q = lane & 3;
    int grow = growbase + r;
    if (grow < N) {
      const float* cp = &cst[w][r][q * 32];
      const float* asp = a_src + q * 32;
      const float* adp = a_dst + q * 32;
      f16x8* hp = (f16x8*)(Hh + (size_t)grow * 128 + q * 32);
      float ss = 0.f, sd = 0.f;
#pragma unroll
      for (int g = 0; g < 4; ++g) {
        f16x8 hv;
#pragma unroll
        for (int jj = 0; jj < 8; ++jj) {
          float v = cp[g * 8 + jj];
          ss = fmaf(v, asp[g * 8 + jj], ss);
          sd = fmaf(v, adp[g * 8 + jj], sd);
          hv[jj] = (halfT)v;
        }
        hp[g] = hv;
      }
      ssrc[grow * 4 + q] = ss;
      sdst[grow * 4 + q] = sd;
    }
    __syncthreads();
  }
}

// ---- scatter into fixed-capacity bucket windows; block-exclusive runs ------
__global__ __launch_bounds__(256) void scatter64_kernel(
    const int* __restrict__ src, const int* __restrict__ dst,
    int* __restrict__ bcur, unsigned* __restrict__ epack,
    int Etot, int E, int NB) {
  __shared__ int h[MAXNB];
  __shared__ int cur[MAXNB];
  int t = threadIdx.x;
  int e0 = blockIdx.x * SCHUNK;
  int e1 = min(e0 + SCHUNK, Etot);
  for (int i = t; i < NB; i += 256) h[i] = 0;
  __syncthreads();
  for (int e = e0 + t; e < e1; e += 256) {
    int d = (e < E) ? dst[e] : (e - E);
    atomicAdd(&h[d >> 6], 1);
  }
  __syncthreads();
  for (int i = t; i < NB; i += 256) {
    int c = h[i];
    cur[i] = c ? atomicAdd(&bcur[i], c) : 0;  // bucket-local base
  }
  __syncthreads();
  for (int e = e0 + t; e < e1; e += 256) {
    int s = (e < E) ? src[e] : (e - E);
    int d = (e < E) ? dst[e] : (e - E);
    int b = d >> 6;
    int pos = atomicAdd(&cur[b], 1);
    if (pos < BCAP)  // overflow guard (never hit for this input)
      epack[(size_t)b * BCAP + pos] = ((unsigned)(d & 63) << 26) | (unsigned)s;
  }
}

// ---- per-bucket counting sort -> node-grouped csr_src + int2 rowinfo -------
__global__ __launch_bounds__(256) void bucket_sort_kernel(
    const unsigned* __restrict__ epack, const int* __restrict__ bcur,
    int* __restrict__ csr_src, int2* __restrict__ rowinfo, int N) {
  __shared__ int cnt[64];
  __shared__ int cur[64];
  __shared__ int cstart[64];
  int t = threadIdx.x;
  int b = blockIdx.x;
  int wbase = b * BCAP;
  int ec = min(bcur[b], BCAP);
  if (t < 64) cnt[t] = 0;
  __syncthreads();
  for (int e = t; e < ec; e += 256)
    atomicAdd(&cnt[epack[wbase + e] >> 26], 1);
  __syncthreads();
  if (t == 0) {
    int run = wbase;
    for (int i = 0; i < 64; ++i) { cur[i] = run; cstart[i] = run; run += cnt[i]; }
  }
  __syncthreads();
  if (t < 64) {
    int gn = b * 64 + t;
    if (gn < N) rowinfo[gn] = make_int2(cstart[t], cnt[t]);
  }
  for (int e = t; e < ec; e += 256) {
    unsigned pk = epack[wbase + e];
    int pos = atomicAdd(&cur[pk >> 26], 1);
    csr_src[pos] = (int)(pk & 0x3FFFFFFu);
  }
}

// ---------------- fused aggregation: one wave per dst node, unroll-8 --------
template <int FINAL>
__global__ __launch_bounds__(256) void agg_kernel(
    const int2* __restrict__ rowinfo, const int* __restrict__ csr_src,
    const float* __restrict__ ssrc, const float* __restrict__ sdst,
    const halfT* __restrict__ Hin, const float* __restrict__ bias,
    const float* __restrict__ lw, const float* __restrict__ lb,
    float* __restrict__ out, int N) {
  __shared__ float4 pbuf[4][64];
  int wid = threadIdx.x >> 6;
  int n = blockIdx.x * 4 + wid;
  if (n >= N) return;
  int lane = threadIdx.x & 63;
  int head = lane >> 4;
  int2 ri = rowinfo[n];
  int base = ri.x, deg = ri.y;
  float4 sd = ((const float4*)sdst)[n];
  const float* pb = (const float*)&pbuf[wid][0];

  float z0 = 0.f, z1 = 0.f, z2 = 0.f, z3 = 0.f;
  float ax = 0.f, ay = 0.f;

  for (int c = 0; c < deg; c += 64) {
    int i = c + lane;
    int sreg = 0;
    if (i < deg) {
      sreg = csr_src[base + i];
      float4 ss = ((const float4*)ssrc)[sreg];
      float e0 = ss.x + sd.x, e1 = ss.y + sd.y;
      float e2 = ss.z + sd.z, e3 = ss.w + sd.w;
      e0 = e0 > 0.f ? e0 : 0.2f * e0;
      e1 = e1 > 0.f ? e1 : 0.2f * e1;
      e2 = e2 > 0.f ? e2 : 0.2f * e2;
      e3 = e3 > 0.f ? e3 : 0.2f * e3;
      float p0 = __expf(e0), p1 = __expf(e1);
      float p2 = __expf(e2), p3 = __expf(e3);
      z0 += p0; z1 += p1; z2 += p2; z3 += p3;
      pbuf[wid][lane] = make_float4(p0, p1, p2, p3);
    }
    int cl = min(64, deg - c);
    int k = 0;
    for (; k + 8 <= cl; k += 8) {
      int sA[8];
      f16x2 vA[8];
#pragma unroll
      for (int u = 0; u < 8; ++u) sA[u] = __shfl(sreg, k + u);
#pragma unroll
      for (int u = 0; u < 8; ++u)
        vA[u] = ((const f16x2*)(Hin + ((size_t)sA[u] << 7)))[lane];
#pragma unroll
      for (int u = 0; u < 8; ++u) {
        float q = pb[(k + u) * 4 + head];
        ax = fmaf(q, (float)vA[u][0], ax);
        ay = fmaf(q, (float)vA[u][1], ay);
      }
    }
    for (; k + 4 <= cl; k += 4) {
      int s0 = __shfl(sreg, k);
      int s1 = __shfl(sreg, k + 1);
      int s2 = __shfl(sreg, k + 2);
      int s3 = __shfl(sreg, k + 3);
      f16x2 v0 = ((const f16x2*)(Hin + ((size_t)s0 << 7)))[lane];
      f16x2 v1 = ((const f16x2*)(Hin + ((size_t)s1 << 7)))[lane];
      f16x2 v2 = ((const f16x2*)(Hin + ((size_t)s2 << 7)))[lane];
      f16x2 v3 = ((const f16x2*)(Hin + ((size_t)s3 << 7)))[lane];
      float q0 = pb[k * 4 + head];
      float q1 = pb[(k + 1) * 4 + head];
      float q2 = pb[(k + 2) * 4 + head];
      float q3 = pb[(k + 3) * 4 + head];
      ax = fmaf(q0, (float)v0[0], ax); ay = fmaf(q0, (float)v0[1], ay);
      ax = fmaf(q1, (float)v1[0], ax); ay = fmaf(q1, (float)v1[1], ay);
      ax = fmaf(q2, (float)v2[0], ax); ay = fmaf(q2, (float)v2[1], ay);
      ax = fmaf(q3, (float)v3[0], ax); ay = fmaf(q3, (float)v3[1], ay);
    }
    for (; k < cl; ++k) {
      int s0 = __shfl(sreg, k);
      f16x2 v0 = ((const f16x2*)(Hin + ((size_t)s0 << 7)))[lane];
      float q0 = pb[k * 4 + head];
      ax = fmaf(q0, (float)v0[0], ax); ay = fmaf(q0, (float)v0[1], ay);
    }
  }

#pragma unroll
  for (int off = 32; off; off >>= 1) {
    z0 += __shfl_xor(z0, off);
    z1 += __shfl_xor(z1, off);
    z2 += __shfl_xor(z2, off);
    z3 += __shfl_xor(z3, off);
  }
  float zz = (head == 0) ? z0 : (head == 1) ? z1 : (head == 2) ? z2 : z3;
  float rz = 1.f / (zz + 1e-16f);
  float2 bb = ((const float2*)bias)[lane];
  float ox = fmaxf(fmaf(ax, rz, bb.x), 0.f);
  float oy = fmaxf(fmaf(ay, rz, bb.y), 0.f);

  if (FINAL) {
    float2 ww = ((const float2*)lw)[lane];
    float v = ox * ww.x + oy * ww.y;
#pragma unroll
    for (int off = 32; off; off >>= 1) v += __shfl_down(v, off);
    if (lane == 0) out[n] = v + lb[0];
  } else {
    ((f16x2*)out)[(size_t)n * 64 + lane] = (f16x2){(halfT)ox, (halfT)oy};
  }
}

extern "C" void kernel_launch(void* const* d_in, const int* in_sizes, int n_in,
                              void* d_out, int out_size, void* d_ws, size_t ws_size,
                              hipStream_t stream) {
  const float* x   = (const float*)d_in[0];
  const int*   src = (const int*)d_in[1];
  const int*   dst = (const int*)d_in[2];
  const float* W1  = (const float*)d_in[3];
  const float* as1 = (const float*)d_in[4];
  const float* ad1 = (const float*)d_in[5];
  const float* b1  = (const float*)d_in[6];
  const float* W2  = (const float*)d_in[7];
  const float* as2 = (const float*)d_in[8];
  const float* ad2 = (const float*)d_in[9];
  const float* b2  = (const float*)d_in[10];
  const float* lw  = (const float*)d_in[11];
  const float* lb  = (const float*)d_in[12];

  int N = in_sizes[0] / 128;
  int E = in_sizes[1];
  int Etot = E + N;
  int NB = (N + 63) / 64;
  int nb128 = (N + 127) / 128;
  int Npad = nb128 * 128;

  char* w = (char*)d_ws;
  halfT* h16  = (halfT*)w; w += (size_t)Npad * 128 * 2;
  halfT* xb16 = (halfT*)w; w += (size_t)Npad * 128 * 2;
  halfT* wf1  = (halfT*)w; w += 16384 * 2;
  halfT* wf2  = (halfT*)w; w += 16384 * 2;
  float* ssrc = (float*)w; w += (size_t)N * 4 * 4;
  float* sdst = (float*)w; w += (size_t)N * 4 * 4;
  int* bcur   = (int*)w;   w += MAXNB * 4;
  int2* rowinfo = (int2*)w; w += (size_t)(N + 64) * 8;
  unsigned* epack = (unsigned*)w; w += (size_t)NB * BCAP * 4;
  int* csr_src = (int*)w;  w += (size_t)NB * BCAP * 4;

  int sc_grid  = (Etot + SCHUNK - 1) / SCHUNK;
  int agg_grid = (N + 3) / 4;

  // ---- prep: W casts + cursor zero (1 dispatch) ----
  prep_kernel<<<129, 256, 0, stream>>>(W1, W2, wf1, wf2, bcur);

  // ---- bucket build (2 dispatches, reused by both layers) ----
  scatter64_kernel<<<sc_grid, 256, 0, stream>>>(src, dst, bcur, epack, Etot, E, NB);
  bucket_sort_kernel<<<NB, 256, 0, stream>>>(epack, bcur, csr_src, rowinfo, N);

  // ---- Layer 1 (gemm reads fp32 x directly, casts in-register) ----
  gemm_mfma_kernel<1><<<nb128, 256, 0, stream>>>(x, nullptr, wf1, as1, ad1,
                                                 h16, ssrc, sdst, N);
  agg_kernel<0><<<agg_grid, 256, 0, stream>>>(rowinfo, csr_src, ssrc, sdst, h16,
                                              b1, nullptr, nullptr, (float*)xb16, N);

  // ---- Layer 2 (fused final linear) ----
  gemm_mfma_kernel<0><<<nb128, 256, 0, stream>>>(nullptr, xb16, wf2, as2, ad2,
                                                 h16, ssrc, sdst, N);
  agg_kernel<1><<<agg_grid, 256, 0, stream>>>(rowinfo, csr_src, ssrc, sdst, h16,
                                              b2, lw, lb, (float*)d_out, N);
}

// Round 12
// 147.981 us; speedup vs baseline: 10.8780x; 1.0096x over previous
//
#include <hip/hip_runtime.h>

// GAT 2-layer v11: v10 with SCHUNK 4096->2048 (scatter64 parallelism).
// fp16 rows + MFMA gemm + per-wave CSR gather agg (BW-bound, at floor).
// N=50000, E=800000 (+N self loops), H=4 heads, C=32, HC=128.

typedef float f32x4 __attribute__((ext_vector_type(4)));
typedef _Float16 f16x8 __attribute__((ext_vector_type(8)));
typedef _Float16 f16x2 __attribute__((ext_vector_type(2)));
typedef _Float16 halfT;

#define SCHUNK 2048
#define MAXNB 1024   // 64-node buckets; supports N <= 65536
#define BCAP 2048    // slots per bucket window (expected ~1088, 29-sigma margin)

// ---- prep: cast W1+W2 to B-fragment order fp16; zero bucket cursors --------
__global__ __launch_bounds__(256) void prep_kernel(
    const float* __restrict__ W1, const float* __restrict__ W2,
    halfT* __restrict__ wf1, halfT* __restrict__ wf2, int* __restrict__ bcur) {
  int b = blockIdx.x;
  if (b < 128) {
    int idx = b * 256 + threadIdx.x;  // 0..32767
    const float* W = (idx < 16384) ? W1 : W2;
    halfT* wf = (idx < 16384) ? wf1 : wf2;
    int i = idx & 16383;
    int j = i & 7, lane = (i >> 3) & 63, ks = (i >> 9) & 3, nt = i >> 11;
    int k = ks * 32 + (lane >> 4) * 8 + j;
    int n = nt * 16 + (lane & 15);
    wf[i] = (halfT)W[k * 128 + n];
  } else {
    for (int i = threadIdx.x; i < MAXNB; i += 256) bcur[i] = 0;
  }
}

// ------- MFMA GEMM + scores: 128 rows/block (2 tiles), optional fp32-A cast
template <int CAST>
__global__ __launch_bounds__(256) void gemm_mfma_kernel(
    const float* __restrict__ Xf, const halfT* __restrict__ Xh,
    const halfT* __restrict__ Wf,
    const float* __restrict__ a_src, const float* __restrict__ a_dst,
    halfT* __restrict__ Hh, float* __restrict__ ssrc, float* __restrict__ sdst,
    int N) {
  __shared__ f16x8 wlds[2048];
  __shared__ float cst[4][16][134];
  int t = threadIdx.x;
  for (int i = t; i < 2048; i += 256) wlds[i] = ((const f16x8*)Wf)[i];
  __syncthreads();

  int w = t >> 6, lane = t & 63;

  for (int tile = 0; tile < 2; ++tile) {
    int growbase = blockIdx.x * 128 + tile * 64 + w * 16;
    int arow = growbase + (lane & 15);
    if (arow > N - 1) arow = N - 1;  // clamp: no OOB reads

    f32x4 acc[8];
#pragma unroll
    for (int nt = 0; nt < 8; ++nt) acc[nt] = (f32x4){0.f, 0.f, 0.f, 0.f};

#pragma unroll
    for (int ks = 0; ks < 4; ++ks) {
      f16x8 af;
      if (CAST) {
        const f32x4* xr = (const f32x4*)(Xf + (size_t)arow * 128 + (lane >> 4) * 8);
        f32x4 a = xr[ks * 8];
        f32x4 b = xr[ks * 8 + 1];
        af[0] = (halfT)a.x; af[1] = (halfT)a.y; af[2] = (halfT)a.z; af[3] = (halfT)a.w;
        af[4] = (halfT)b.x; af[5] = (halfT)b.y; af[6] = (halfT)b.z; af[7] = (halfT)b.w;
      } else {
        const f16x8* xr = (const f16x8*)(Xh + (size_t)arow * 128 + (lane >> 4) * 8);
        af = xr[ks * 4];
      }
#pragma unroll
      for (int nt = 0; nt < 8; ++nt)
        acc[nt] = __builtin_amdgcn_mfma_f32_16x16x32_f16(
            af, wlds[(nt * 4 + ks) * 64 + lane], acc[nt], 0, 0, 0);
    }

#pragma unroll
    for (int nt = 0; nt < 8; ++nt)
#pragma unroll
      for (int j = 0; j < 4; ++j)
        cst[w][(lane >> 4) * 4 + j][nt * 16 + (lane & 15)] = acc[nt][j];
    __syncthreads();

    int r = lane >> 2, q = lane & 3;
    int grow = growbase + r;
    if (grow < N) {
      const float* cp = &cst[w][r][q * 32];
      const float* asp = a_src + q * 32;
      const float* adp = a_dst + q * 32;
      f16x8* hp = (f16x8*)(Hh + (size_t)grow * 128 + q * 32);
      float ss = 0.f, sd = 0.f;
#pragma unroll
      for (int g = 0; g < 4; ++g) {
        f16x8 hv;
#pragma unroll
        for (int jj = 0; jj < 8; ++jj) {
          float v = cp[g * 8 + jj];
          ss = fmaf(v, asp[g * 8 + jj], ss);
          sd = fmaf(v, adp[g * 8 + jj], sd);
          hv[jj] = (halfT)v;
        }
        hp[g] = hv;
      }
      ssrc[grow * 4 + q] = ss;
      sdst[grow * 4 + q] = sd;
    }
    __syncthreads();
  }
}

// ---- scatter into fixed-capacity bucket windows; block-exclusive runs ------
__global__ __launch_bounds__(256) void scatter64_kernel(
    const int* __restrict__ src, const int* __restrict__ dst,
    int* __restrict__ bcur, unsigned* __restrict__ epack,
    int Etot, int E, int NB) {
  __shared__ int h[MAXNB];
  __shared__ int cur[MAXNB];
  int t = threadIdx.x;
  int e0 = blockIdx.x * SCHUNK;
  int e1 = min(e0 + SCHUNK, Etot);
  for (int i = t; i < NB; i += 256) h[i] = 0;
  __syncthreads();
  for (int e = e0 + t; e < e1; e += 256) {
    int d = (e < E) ? dst[e] : (e - E);
    atomicAdd(&h[d >> 6], 1);
  }
  __syncthreads();
  for (int i = t; i < NB; i += 256) {
    int c = h[i];
    cur[i] = c ? atomicAdd(&bcur[i], c) : 0;  // bucket-local base
  }
  __syncthreads();
  for (int e = e0 + t; e < e1; e += 256) {
    int s = (e < E) ? src[e] : (e - E);
    int d = (e < E) ? dst[e] : (e - E);
    int b = d >> 6;
    int pos = atomicAdd(&cur[b], 1);
    if (pos < BCAP)  // overflow guard (never hit for this input)
      epack[(size_t)b * BCAP + pos] = ((unsigned)(d & 63) << 26) | (unsigned)s;
  }
}

// ---- per-bucket counting sort -> node-grouped csr_src + int2 rowinfo -------
__global__ __launch_bounds__(256) void bucket_sort_kernel(
    const unsigned* __restrict__ epack, const int* __restrict__ bcur,
    int* __restrict__ csr_src, int2* __restrict__ rowinfo, int N) {
  __shared__ int cnt[64];
  __shared__ int cur[64];
  __shared__ int cstart[64];
  int t = threadIdx.x;
  int b = blockIdx.x;
  int wbase = b * BCAP;
  int ec = min(bcur[b], BCAP);
  if (t < 64) cnt[t] = 0;
  __syncthreads();
  for (int e = t; e < ec; e += 256)
    atomicAdd(&cnt[epack[wbase + e] >> 26], 1);
  __syncthreads();
  if (t == 0) {
    int run = wbase;
    for (int i = 0; i < 64; ++i) { cur[i] = run; cstart[i] = run; run += cnt[i]; }
  }
  __syncthreads();
  if (t < 64) {
    int gn = b * 64 + t;
    if (gn < N) rowinfo[gn] = make_int2(cstart[t], cnt[t]);
  }
  for (int e = t; e < ec; e += 256) {
    unsigned pk = epack[wbase + e];
    int pos = atomicAdd(&cur[pk >> 26], 1);
    csr_src[pos] = (int)(pk & 0x3FFFFFFu);
  }
}

// ---------------- fused aggregation: one wave per dst node, unroll-8 --------
template <int FINAL>
__global__ __launch_bounds__(256) void agg_kernel(
    const int2* __restrict__ rowinfo, const int* __restrict__ csr_src,
    const float* __restrict__ ssrc, const float* __restrict__ sdst,
    const halfT* __restrict__ Hin, const float* __restrict__ bias,
    const float* __restrict__ lw, const float* __restrict__ lb,
    float* __restrict__ out, int N) {
  __shared__ float4 pbuf[4][64];
  int wid = threadIdx.x >> 6;
  int n = blockIdx.x * 4 + wid;
  if (n >= N) return;
  int lane = threadIdx.x & 63;
  int head = lane >> 4;
  int2 ri = rowinfo[n];
  int base = ri.x, deg = ri.y;
  float4 sd = ((const float4*)sdst)[n];
  const float* pb = (const float*)&pbuf[wid][0];

  float z0 = 0.f, z1 = 0.f, z2 = 0.f, z3 = 0.f;
  float ax = 0.f, ay = 0.f;

  for (int c = 0; c < deg; c += 64) {
    int i = c + lane;
    int sreg = 0;
    if (i < deg) {
      sreg = csr_src[base + i];
      float4 ss = ((const float4*)ssrc)[sreg];
      float e0 = ss.x + sd.x, e1 = ss.y + sd.y;
      float e2 = ss.z + sd.z, e3 = ss.w + sd.w;
      e0 = e0 > 0.f ? e0 : 0.2f * e0;
      e1 = e1 > 0.f ? e1 : 0.2f * e1;
      e2 = e2 > 0.f ? e2 : 0.2f * e2;
      e3 = e3 > 0.f ? e3 : 0.2f * e3;
      float p0 = __expf(e0), p1 = __expf(e1);
      float p2 = __expf(e2), p3 = __expf(e3);
      z0 += p0; z1 += p1; z2 += p2; z3 += p3;
      pbuf[wid][lane] = make_float4(p0, p1, p2, p3);
    }
    int cl = min(64, deg - c);
    int k = 0;
    for (; k + 8 <= cl; k += 8) {
      int sA[8];
      f16x2 vA[8];
#pragma unroll
      for (int u = 0; u < 8; ++u) sA[u] = __shfl(sreg, k + u);
#pragma unroll
      for (int u = 0; u < 8; ++u)
        vA[u] = ((const f16x2*)(Hin + ((size_t)sA[u] << 7)))[lane];
#pragma unroll
      for (int u = 0; u < 8; ++u) {
        float q = pb[(k + u) * 4 + head];
        ax = fmaf(q, (float)vA[u][0], ax);
        ay = fmaf(q, (float)vA[u][1], ay);
      }
    }
    for (; k + 4 <= cl; k += 4) {
      int s0 = __shfl(sreg, k);
      int s1 = __shfl(sreg, k + 1);
      int s2 = __shfl(sreg, k + 2);
      int s3 = __shfl(sreg, k + 3);
      f16x2 v0 = ((const f16x2*)(Hin + ((size_t)s0 << 7)))[lane];
      f16x2 v1 = ((const f16x2*)(Hin + ((size_t)s1 << 7)))[lane];
      f16x2 v2 = ((const f16x2*)(Hin + ((size_t)s2 << 7)))[lane];
      f16x2 v3 = ((const f16x2*)(Hin + ((size_t)s3 << 7)))[lane];
      float q0 = pb[k * 4 + head];
      float q1 = pb[(k + 1) * 4 + head];
      float q2 = pb[(k + 2) * 4 + head];
      float q3 = pb[(k + 3) * 4 + head];
      ax = fmaf(q0, (float)v0[0], ax); ay = fmaf(q0, (float)v0[1], ay);
      ax = fmaf(q1, (float)v1[0], ax); ay = fmaf(q1, (float)v1[1], ay);
      ax = fmaf(q2, (float)v2[0], ax); ay = fmaf(q2, (float)v2[1], ay);
      ax = fmaf(q3, (float)v3[0], ax); ay = fmaf(q3, (float)v3[1], ay);
    }
    for (; k < cl; ++k) {
      int s0 = __shfl(sreg, k);
      f16x2 v0 = ((const f16x2*)(Hin + ((size_t)s0 << 7)))[lane];
      float q0 = pb[k * 4 + head];
      ax = fmaf(q0, (float)v0[0], ax); ay = fmaf(q0, (float)v0[1], ay);
    }
  }

#pragma unroll
  for (int off = 32; off; off >>= 1) {
    z0 += __shfl_xor(z0, off);
    z1 += __shfl_xor(z1, off);
    z2 += __shfl_xor(z2, off);
    z3 += __shfl_xor(z3, off);
  }
  float zz = (head == 0) ? z0 : (head == 1) ? z1 : (head == 2) ? z2 : z3;
  float rz = 1.f / (zz + 1e-16f);
  float2 bb = ((const float2*)bias)[lane];
  float ox = fmaxf(fmaf(ax, rz, bb.x), 0.f);
  float oy = fmaxf(fmaf(ay, rz, bb.y), 0.f);

  if (FINAL) {
    float2 ww = ((const float2*)lw)[lane];
    float v = ox * ww.x + oy * ww.y;
#pragma unroll
    for (int off = 32; off; off >>= 1) v += __shfl_down(v, off);
    if (lane == 0) out[n] = v + lb[0];
  } else {
    ((f16x2*)out)[(size_t)n * 64 + lane] = (f16x2){(halfT)ox, (halfT)oy};
  }
}

extern "C" void kernel_launch(void* const* d_in, const int* in_sizes, int n_in,
                              void* d_out, int out_size, void* d_ws, size_t ws_size,
                              hipStream_t stream) {
  const float* x   = (const float*)d_in[0];
  const int*   src = (const int*)d_in[1];
  const int*   dst = (const int*)d_in[2];
  const float* W1  = (const float*)d_in[3];
  const float* as1 = (const float*)d_in[4];
  const float* ad1 = (const float*)d_in[5];
  const float* b1  = (const float*)d_in[6];
  const float* W2  = (const float*)d_in[7];
  const float* as2 = (const float*)d_in[8];
  const float* ad2 = (const float*)d_in[9];
  const float* b2  = (const float*)d_in[10];
  const float* lw  = (const float*)d_in[11];
  const float* lb  = (const float*)d_in[12];

  int N = in_sizes[0] / 128;
  int E = in_sizes[1];
  int Etot = E + N;
  int NB = (N + 63) / 64;
  int nb128 = (N + 127) / 128;
  int Npad = nb128 * 128;

  char* w = (char*)d_ws;
  halfT* h16  = (halfT*)w; w += (size_t)Npad * 128 * 2;
  halfT* xb16 = (halfT*)w; w += (size_t)Npad * 128 * 2;
  halfT* wf1  = (halfT*)w; w += 16384 * 2;
  halfT* wf2  = (halfT*)w; w += 16384 * 2;
  float* ssrc = (float*)w; w += (size_t)N * 4 * 4;
  float* sdst = (float*)w; w += (size_t)N * 4 * 4;
  int* bcur   = (int*)w;   w += MAXNB * 4;
  int2* rowinfo = (int2*)w; w += (size_t)(N + 64) * 8;
  unsigned* epack = (unsigned*)w; w += (size_t)NB * BCAP * 4;
  int* csr_src = (int*)w;  w += (size_t)NB * BCAP * 4;

  int sc_grid  = (Etot + SCHUNK - 1) / SCHUNK;
  int agg_grid = (N + 3) / 4;

  // ---- prep: W casts + cursor zero (1 dispatch) ----
  prep_kernel<<<129, 256, 0, stream>>>(W1, W2, wf1, wf2, bcur);

  // ---- bucket build (2 dispatches, reused by both layers) ----
  scatter64_kernel<<<sc_grid, 256, 0, stream>>>(src, dst, bcur, epack, Etot, E, NB);
  bucket_sort_kernel<<<NB, 256, 0, stream>>>(epack, bcur, csr_src, rowinfo, N);

  // ---- Layer 1 (gemm reads fp32 x directly, casts in-register) ----
  gemm_mfma_kernel<1><<<nb128, 256, 0, stream>>>(x, nullptr, wf1, as1, ad1,
                                                 h16, ssrc, sdst, N);
  agg_kernel<0><<<agg_grid, 256, 0, stream>>>(rowinfo, csr_src, ssrc, sdst, h16,
                                              b1, nullptr, nullptr, (float*)xb16, N);

  // ---- Layer 2 (fused final linear) ----
  gemm_mfma_kernel<0><<<nb128, 256, 0, stream>>>(nullptr, xb16, wf2, as2, ad2,
                                                 h16, ssrc, sdst, N);
  agg_kernel<1><<<agg_grid, 256, 0, stream>>>(rowinfo, csr_src, ssrc, sdst, h16,
                                              b2, lw, lb, (float*)d_out, N);
}